// Round 13
// baseline (764.298 us; speedup 1.0000x reference)
//
#include <hip/hip_runtime.h>
#include <math.h>

// Problem constants
#define B_ 8
#define N_ 2048
#define HD_ 512
#define H_ 8
#define M_ 128
#define VD_ 64
// LAM = 0.01, EPS = 0.002 ; LAM/EPS = 5 ; 1/EPS = 500 ; 1/(100*EPS^2) = 2500
// Workspace: ~57.2M floats (~229 MB) — under the 256MiB d_ws.
//
// Packed bf16 tensor layout ("PT3"): linear = (npack*NR + R)*4 + e, n=npack*4+e.
// PT: NR=8192, R=bh*128+m. VT: NR=4096, R=bh*64+d.
//
// ROUND 13 CHANGE (single variable): chol4 + solve5 -> 512 threads/block.
// Both are latency-bound; parallel phases (loads, rank-16 update, panel
// staging, writeback) halve their per-thread iteration counts. Serial
// diag/substitution chains unchanged. Same LDS, same algorithm.

typedef __attribute__((ext_vector_type(8))) short short8v;   // 8 bf16 (4 VGPRs)
typedef __attribute__((ext_vector_type(4))) float f32x4;

__device__ __forceinline__ unsigned short f2bf(float f) {
  unsigned u = __float_as_uint(f);
  u += 0x7FFF + ((u >> 16) & 1);   // round-to-nearest-even
  return (unsigned short)(u >> 16);
}
__device__ __forceinline__ float bf2f(unsigned short h) {
  return __uint_as_float(((unsigned)h) << 16);
}

// async global->LDS, 16B per lane; lptr must be wave-uniform base (lane*16 added by HW)
__device__ __forceinline__ void gload16(const unsigned short* g, unsigned short* l) {
  __builtin_amdgcn_global_load_lds(
      (const __attribute__((address_space(1))) unsigned int*)g,
      (__attribute__((address_space(3))) unsigned int*)l, 16, 0, 0);
}

// ---------------------------------------------------------------------------
// Split fp32 -> (hi, lo) bf16 pair.
// ---------------------------------------------------------------------------
__global__ __launch_bounds__(256) void split_kernel(
    const float* __restrict__ in, unsigned short* __restrict__ hi,
    unsigned short* __restrict__ lo, int n)
{
  const int i = (blockIdx.x * 256 + threadIdx.x) << 2;
  if (i >= n) return;
  float4 v = *(const float4*)(in + i);
  ushort4 h, l;
  h.x = f2bf(v.x); l.x = f2bf(v.x - bf2f(h.x));
  h.y = f2bf(v.y); l.y = f2bf(v.y - bf2f(h.y));
  h.z = f2bf(v.z); l.z = f2bf(v.z - bf2f(h.z));
  h.w = f2bf(v.w); l.w = f2bf(v.w - bf2f(h.w));
  *(ushort4*)(hi + i) = h;
  *(ushort4*)(lo + i) = l;
}

// ---------------------------------------------------------------------------
// Combined RFF weights: WOmT[path][hm][p] = sum_d W[h*64+d][p]*omega[d][m]
// ---------------------------------------------------------------------------
__global__ __launch_bounds__(256) void womb_kernel(
    const float* __restrict__ Wq, const float* __restrict__ Wk, const float* __restrict__ Wx0,
    const float* __restrict__ bq, const float* __restrict__ bk, const float* __restrict__ bx0,
    const float* __restrict__ omega, const float* __restrict__ brff,
    unsigned short* __restrict__ WOmH, unsigned short* __restrict__ WOmL,
    float* __restrict__ bias2)
{
  const int blk = blockIdx.x, tid = threadIdx.x;
  const int path = blk >> 10, hm = blk & 1023;
  const int h = hm >> 7, m = hm & 127;
  const float* W  = (path == 0) ? Wq : (path == 1) ? Wk : Wx0;
  const float* bv = (path == 0) ? bq : (path == 1) ? bk : bx0;
  __shared__ float om[64];
  if (tid < 64) om[tid] = omega[tid * 128 + m];
  __syncthreads();
  for (int c = tid; c < 512; c += 256) {
    float s = 0.f;
#pragma unroll 8
    for (int d = 0; d < 64; ++d) s = fmaf(W[(h * 64 + d) * 512 + c], om[d], s);
    const unsigned short sh = f2bf(s);
    const size_t o = (size_t)(path * 1024 + hm) * 512 + c;
    WOmH[o] = sh;
    WOmL[o] = f2bf(s - bf2f(sh));
  }
  if (tid == 0) {
    float s = 0.f;
    for (int d = 0; d < 64; ++d) s = fmaf(bv[h * 64 + d], om[d], s);
    bias2[path * 1024 + hm] = s + brff[m];
  }
}

// ---------------------------------------------------------------------------
// bf16x3 MFMA GEMM core (128x128 tile, 256 thr, K=512), gload_lds staging.
// ---------------------------------------------------------------------------
#define LDP 32
#define GEMM_PROLOGUE(NCOLBITS)                                              \
  __shared__ unsigned short Ah[128 * LDP], Al[128 * LDP];                    \
  __shared__ unsigned short Bh[128 * LDP], Bl[128 * LDP];                    \
  const int tid = threadIdx.x;                                               \
  const int bx = blockIdx.x & ((1 << (NCOLBITS)) - 1);                       \
  const int by = blockIdx.x >> (NCOLBITS);                                   \
  const int row0 = by << 7, col0 = bx << 7;                                  \
  const int lane = tid & 63, wave = tid >> 6;                                \
  const int wr = wave >> 1, wc = wave & 1;                                   \
  const int fr = lane & 15, fk = (lane >> 4) << 3;                           \
  f32x4 acc[4][4];                                                           \
  _Pragma("unroll") for (int i = 0; i < 4; ++i)                              \
  _Pragma("unroll") for (int j = 0; j < 4; ++j)                              \
      acc[i][j] = (f32x4){0.f, 0.f, 0.f, 0.f};                               \
  const int srow = tid >> 2;                                                 \
  const int sch = (tid & 3) << 3;                                            \
  const size_t ga = (size_t)(row0 + srow) * 512 + sch;                       \
  const size_t gb = (size_t)(col0 + srow) * 512 + sch;                       \
  const int ldw = wave * 512;   /* wave-uniform ushort offset (1KB/wave) */

#define GEMM_KLOOP                                                           \
  for (int kt = 0; kt < 16; ++kt) {                                          \
    const int kko = kt * 32;                                                 \
    __syncthreads();                                                         \
    gload16(Ahi + ga + kko,                    Ah + ldw);                    \
    gload16(Ahi + ga + (size_t)64 * 512 + kko, Ah + 64 * LDP + ldw);         \
    gload16(Alo + ga + kko,                    Al + ldw);                    \
    gload16(Alo + ga + (size_t)64 * 512 + kko, Al + 64 * LDP + ldw);         \
    gload16(Bhi + gb + kko,                    Bh + ldw);                    \
    gload16(Bhi + gb + (size_t)64 * 512 + kko, Bh + 64 * LDP + ldw);         \
    gload16(Blo + gb + kko,                    Bl + ldw);                    \
    gload16(Blo + gb + (size_t)64 * 512 + kko, Bl + 64 * LDP + ldw);         \
    __syncthreads();                                                         \
    short8v a_hi[4], a_lo[4];                                                \
    _Pragma("unroll") for (int i = 0; i < 4; ++i) {                          \
      const int ar = (wr * 64 + i * 16 + fr) * LDP + fk;                     \
      a_hi[i] = *(const short8v*)&Ah[ar];                                    \
      a_lo[i] = *(const short8v*)&Al[ar];                                    \
    }                                                                        \
    _Pragma("unroll") for (int j = 0; j < 4; ++j) {                          \
      const int br = (wc * 64 + j * 16 + fr) * LDP + fk;                     \
      short8v b_hi = *(const short8v*)&Bh[br];                               \
      short8v b_lo = *(const short8v*)&Bl[br];                               \
      _Pragma("unroll") for (int i = 0; i < 4; ++i) {                        \
        acc[i][j] = __builtin_amdgcn_mfma_f32_16x16x32_bf16(a_hi[i], b_hi, acc[i][j], 0, 0, 0); \
        acc[i][j] = __builtin_amdgcn_mfma_f32_16x16x32_bf16(a_hi[i], b_lo, acc[i][j], 0, 0, 0); \
        acc[i][j] = __builtin_amdgcn_mfma_f32_16x16x32_bf16(a_lo[i], b_hi, acc[i][j], 0, 0, 0); \
      }                                                                      \
    }                                                                        \
  }

// Direct packed-layout store: one ushort4 per (i,j) per lane; consecutive
// lanes contiguous -> 4 x 128B dense segments per wave store instruction.
#define PT3_WRITE(HIbuf, LObuf, RBASE, NR)                                   \
  {                                                                          \
    const int hi4_ = lane >> 4;                                              \
    _Pragma("unroll") for (int j = 0; j < 4; ++j) {                          \
      const int rr = (RBASE) + wc * 64 + j * 16 + fr;                        \
      _Pragma("unroll") for (int i = 0; i < 4; ++i) {                        \
        const int npack = (n0t >> 2) + wr * 16 + hi4_ + i * 4;               \
        ushort4 hv, lv;                                                      \
        hv.x = f2bf(acc[i][j][0]); lv.x = f2bf(acc[i][j][0] - bf2f(hv.x));   \
        hv.y = f2bf(acc[i][j][1]); lv.y = f2bf(acc[i][j][1] - bf2f(hv.y));   \
        hv.z = f2bf(acc[i][j][2]); lv.z = f2bf(acc[i][j][2] - bf2f(hv.z));   \
        hv.w = f2bf(acc[i][j][3]); lv.w = f2bf(acc[i][j][3] - bf2f(hv.w));   \
        const size_t idx = ((size_t)npack * (NR) + rr) << 2;                 \
        *(ushort4*)(HIbuf + idx) = hv;                                       \
        *(ushort4*)(LObuf + idx) = lv;                                       \
      }                                                                      \
    }                                                                        \
  }

// ---------------------------------------------------------------------------
// Final projection (operand-swapped): A = Wo (rows = output cols, 512),
// B = y (rows = output rows, 16384). Lane owns 4 consecutive output cols
// -> float4 stores. grid 512, NCOLBITS=7.
// ---------------------------------------------------------------------------
__global__ __launch_bounds__(256, 1) void gemm_out(
    const unsigned short* __restrict__ Ahi, const unsigned short* __restrict__ Alo,
    const unsigned short* __restrict__ Bhi, const unsigned short* __restrict__ Blo,
    const float* __restrict__ bias, float* __restrict__ Y)
{
  GEMM_PROLOGUE(7)
  GEMM_KLOOP
  const int hi4_ = lane >> 4;
#pragma unroll
  for (int j = 0; j < 4; ++j) {
    const int r = col0 + wc * 64 + j * 16 + fr;
#pragma unroll
    for (int i = 0; i < 4; ++i) {
      const int c0 = row0 + wr * 64 + i * 16 + (hi4_ << 2);
      const float4 bc4 = *(const float4*)(bias + c0);
      float4 o;
      o.x = acc[i][j][0] + bc4.x;
      o.y = acc[i][j][1] + bc4.y;
      o.z = acc[i][j][2] + bc4.z;
      o.w = acc[i][j][3] + bc4.w;
      *(float4*)(Y + (size_t)r * 512 + c0) = o;
    }
  }
}

// ---------------------------------------------------------------------------
// V GEMM: emits VT3 packed (NR=4096, R=b*512+col), v=(acc+bias)*mask[row].
// ---------------------------------------------------------------------------
__global__ __launch_bounds__(256, 1) void gemm_vt(
    const unsigned short* __restrict__ Ahi, const unsigned short* __restrict__ Alo,
    const unsigned short* __restrict__ Bhi, const unsigned short* __restrict__ Blo,
    const float* __restrict__ bias, const float* __restrict__ mask,
    unsigned short* __restrict__ VThi, unsigned short* __restrict__ VTlo)
{
  GEMM_PROLOGUE(2)
  GEMM_KLOOP
  const int b = row0 >> 11;
  const int n0t = row0 & 2047;
  const int hi4 = lane >> 4;
  float mk[4][4];
#pragma unroll
  for (int i = 0; i < 4; ++i)
#pragma unroll
    for (int r = 0; r < 4; ++r)
      mk[i][r] = mask[b * 2048 + n0t + wr * 64 + (hi4 << 2) + i * 16 + r];
#pragma unroll
  for (int j = 0; j < 4; ++j) {
    const float bc = bias[col0 + wc * 64 + j * 16 + fr];
#pragma unroll
    for (int i = 0; i < 4; ++i)
#pragma unroll
      for (int r = 0; r < 4; ++r)
        acc[i][j][r] = (acc[i][j][r] + bc) * mk[i][r];
  }
  PT3_WRITE(VThi, VTlo, b * 512 + col0, 4096)
}

// ---------------------------------------------------------------------------
// Fused head-GEMM + RFF: Phi = 0.125*__cosf(x@WOmT^T + bias2)*mask.
// Emits PT3 packed (NR=8192, R=bh*128+m). grid 1024: 8 head-tiles x 128 rows.
// ---------------------------------------------------------------------------
__global__ __launch_bounds__(256, 1) void gemm_rff(
    const unsigned short* __restrict__ Ahi, const unsigned short* __restrict__ Alo,
    const unsigned short* __restrict__ Bhi, const unsigned short* __restrict__ Blo,
    const float* __restrict__ bias2, const float* __restrict__ mask,
    unsigned short* __restrict__ PThi, unsigned short* __restrict__ PTlo)
{
  GEMM_PROLOGUE(3)
  GEMM_KLOOP
  const int b = row0 >> 11;
  const int n0t = row0 & 2047;
  const int bh = b * 8 + bx;     // col tile == head
  const int hi4 = lane >> 4;
  float mk[4][4];
#pragma unroll
  for (int i = 0; i < 4; ++i)
#pragma unroll
    for (int r = 0; r < 4; ++r)
      mk[i][r] = mask[b * 2048 + n0t + wr * 64 + (hi4 << 2) + i * 16 + r];
#pragma unroll
  for (int j = 0; j < 4; ++j) {
    const float bb = bias2[col0 + wc * 64 + j * 16 + fr];
#pragma unroll
    for (int i = 0; i < 4; ++i)
#pragma unroll
      for (int r = 0; r < 4; ++r)
        acc[i][j][r] = 0.125f * __cosf(acc[i][j][r] + bb) * mk[i][r];
  }
  PT3_WRITE(PThi, PTlo, bh * 128, 8192)
}

// ---------------------------------------------------------------------------
// Combined Gram + PhiT*V partials via MFMA (bf16x3), PT3/VT3 inputs.
// ---------------------------------------------------------------------------
#define GPD 72
__global__ __launch_bounds__(256) void gram_ptv(
    const unsigned short* __restrict__ PThi, const unsigned short* __restrict__ PTlo,
    const unsigned short* __restrict__ VThi, const unsigned short* __restrict__ VTlo,
    float* __restrict__ GPart, float* __restrict__ PPart, int withV)
{
  __shared__ unsigned short Ath[128 * GPD], Atl[128 * GPD];
  __shared__ unsigned short Vh[64 * GPD], Vl[64 * GPD];
  const int bh = blockIdx.x, sp = blockIdx.y, tid = threadIdx.x;
  const int lane = tid & 63, wave = tid >> 6;
  const int wr = wave >> 1, wc = wave & 1;
  const int fr = lane & 15, fk = (lane >> 4) << 3;
  const int skipj = (!withV && wc == 1);
  f32x4 acc[4][6];
#pragma unroll
  for (int i = 0; i < 4; ++i)
#pragma unroll
    for (int j = 0; j < 6; ++j) acc[i][j] = (f32x4){0.f, 0.f, 0.f, 0.f};
  const int sm = tid & 127, sph = tid >> 7;   // PT staging: m, half
  const int sd = tid & 63, spv = tid >> 6;    // V staging: d, quarter
  for (int n0 = sp * 512; n0 < sp * 512 + 512; n0 += 64) {
    __syncthreads();
#pragma unroll
    for (int s = 0; s < 8; ++s) {
      const int npr = sph * 8 + s;
      const size_t idx = ((size_t)((n0 >> 2) + npr) * 8192 + bh * 128 + sm) << 2;
      *(ushort4*)&Ath[sm * GPD + npr * 4] = *(const ushort4*)(PThi + idx);
      *(ushort4*)&Atl[sm * GPD + npr * 4] = *(const ushort4*)(PTlo + idx);
    }
    if (withV) {
#pragma unroll
      for (int s = 0; s < 4; ++s) {
        const int npr = spv * 4 + s;
        const size_t idx = ((size_t)((n0 >> 2) + npr) * 4096 + bh * 64 + sd) << 2;
        *(ushort4*)&Vh[sd * GPD + npr * 4] = *(const ushort4*)(VThi + idx);
        *(ushort4*)&Vl[sd * GPD + npr * 4] = *(const ushort4*)(VTlo + idx);
      }
    }
    __syncthreads();
#pragma unroll
    for (int ks = 0; ks < 2; ++ks) {
      const int ko = fk + (ks << 5);
      short8v a_h[4], a_l[4];
#pragma unroll
      for (int i = 0; i < 4; ++i) {
        const int ar = (wr * 64 + i * 16 + fr) * GPD + ko;
        a_h[i] = *(const short8v*)&Ath[ar];
        a_l[i] = *(const short8v*)&Atl[ar];
      }
#pragma unroll
      for (int j = 0; j < 6; ++j) {
        if (skipj && j >= 2) continue;
        const int c = wc * 96 + j * 16 + fr;
        short8v b_h, b_l;
        if (wc * 96 + j * 16 < 128) {
          b_h = *(const short8v*)&Ath[c * GPD + ko];
          b_l = *(const short8v*)&Atl[c * GPD + ko];
        } else {
          b_h = *(const short8v*)&Vh[(c - 128) * GPD + ko];
          b_l = *(const short8v*)&Vl[(c - 128) * GPD + ko];
        }
#pragma unroll
        for (int i = 0; i < 4; ++i) {
          acc[i][j] = __builtin_amdgcn_mfma_f32_16x16x32_bf16(a_h[i], b_h, acc[i][j], 0, 0, 0);
          acc[i][j] = __builtin_amdgcn_mfma_f32_16x16x32_bf16(a_h[i], b_l, acc[i][j], 0, 0, 0);
          acc[i][j] = __builtin_amdgcn_mfma_f32_16x16x32_bf16(a_l[i], b_h, acc[i][j], 0, 0, 0);
        }
      }
    }
  }
  const int rb = wr * 64 + ((lane >> 4) << 2);
  const size_t gob = (size_t)(sp * 64 + bh) * 16384;
  const size_t pob = (size_t)(sp * 64 + bh) * 8192;
#pragma unroll
  for (int j = 0; j < 6; ++j) {
    if (skipj && j >= 2) continue;
    const int c = wc * 96 + j * 16 + fr;
#pragma unroll
    for (int i = 0; i < 4; ++i) {
      const int m0 = rb + i * 16;
      if (wc * 96 + j * 16 < 128) {
#pragma unroll
        for (int r = 0; r < 4; ++r) GPart[gob + (size_t)(m0 + r) * 128 + c] = acc[i][j][r];
      } else {
#pragma unroll
        for (int r = 0; r < 4; ++r) PPart[pob + (size_t)(m0 + r) * 64 + (c - 128)] = acc[i][j][r];
      }
    }
  }
}

// ---------------------------------------------------------------------------
__global__ __launch_bounds__(256) void reduce4_kernel(
    const float* __restrict__ part, float* __restrict__ out, int n, size_t cs)
{
  const int i = blockIdx.x * 256 + threadIdx.x;
  if (i < n) out[i] = (part[i] + part[cs + i]) + (part[2*cs + i] + part[3*cs + i]);
}

// ---------------------------------------------------------------------------
// yy partials from VT3: yyp[ch*64+bh] = sum over n-chunk of (hi+lo)^2
// ---------------------------------------------------------------------------
__global__ __launch_bounds__(256) void yy_vt(
    const unsigned short* __restrict__ VThi, const unsigned short* __restrict__ VTlo,
    float* __restrict__ yyp)
{
  const int bh = blockIdx.x, ch = blockIdx.y, tid = threadIdx.x;
  float s = 0.f;
  for (int t = tid; t < 4096; t += 256) {
    const int d = t & 63, npr = t >> 6;
    const size_t idx = ((size_t)(ch * 64 + npr) * 4096 + bh * 64 + d) << 2;
    ushort4 h4 = *(const ushort4*)(VThi + idx);
    ushort4 l4 = *(const ushort4*)(VTlo + idx);
    float v;
    v = bf2f(h4.x) + bf2f(l4.x); s = fmaf(v, v, s);
    v = bf2f(h4.y) + bf2f(l4.y); s = fmaf(v, v, s);
    v = bf2f(h4.z) + bf2f(l4.z); s = fmaf(v, v, s);
    v = bf2f(h4.w) + bf2f(l4.w); s = fmaf(v, v, s);
  }
  __shared__ float red[256];
  red[tid] = s; __syncthreads();
  for (int st = 128; st > 0; st >>= 1) {
    if (tid < st) red[tid] += red[tid + st];
    __syncthreads();
  }
  if (tid == 0) yyp[ch * 64 + bh] = red[0];
}

// ---------------------------------------------------------------------------
// Blocked batched Cholesky (NB=16), 512 threads.
// Swizzle f(i)=(i^(i>>2))&7: conflict-free for stride-1 AND stride-4 rows.
// ---------------------------------------------------------------------------
#define SWZ(i) ((((i) ^ ((i) >> 2)) & 7) << 2)
#define ELX(i,j)  As[(((i) << 7) + ((j) ^ SWZ(i)))]
#define EL4P(i,j4) (*(float4*)&As[(((i) << 7) + ((j4) ^ SWZ(i)))])

__global__ __launch_bounds__(512) void chol4_kernel(
    const float* __restrict__ Gk, const float* __restrict__ Go, const float* __restrict__ Cq,
    float* __restrict__ Lk, float* __restrict__ Lo, float* __restrict__ LTq, float* __restrict__ LTk,
    float* __restrict__ ldbuf, float* __restrict__ Dinvb)
{
  __shared__ float As[128*128];
  const int bh = blockIdx.x, which = blockIdx.y, tid = threadIdx.x;
  const float* G1; const float* G2 = nullptr; float* Lout;
  if (which == 0)      { G1 = Gk; Lout = Lk;  }
  else if (which == 1) { G1 = Go; Lout = Lo;  }
  else if (which == 2) { G1 = Go; G2 = Cq; Lout = LTq; }
  else                 { G1 = Go; G2 = Gk; Lout = LTk; }
  const size_t base = (size_t)bh * 16384;
  for (int t = tid; t < 16384; t += 512) {
    float v = G1[base + t];
    if (G2) v = fmaf(5.f, G2[base + t], v);
    const int i = t >> 7, j = t & 127;
    if (i == j) v += 0.01f;
    ELX(i, j) = v;
  }
  __syncthreads();

  float ldacc = 0.f;
  for (int kb = 0; kb < 8; ++kb) {
    const int k0 = kb << 4;
    const int rbase = k0 + 16;
    const int R = 128 - rbase;
    float Dg[16][16];
    float dinv[16];
    if (tid < 128) {
#pragma unroll
      for (int j = 0; j < 16; ++j) {
#pragma unroll
        for (int p4 = 0; p4 < 16; p4 += 4) {
          float4 q = EL4P(k0 + j, k0 + p4);
          Dg[j][p4] = q.x; Dg[j][p4+1] = q.y; Dg[j][p4+2] = q.z; Dg[j][p4+3] = q.w;
        }
      }
#pragma unroll
      for (int kk = 0; kk < 16; ++kk) {
        const float d = sqrtf(Dg[kk][kk]);
        Dg[kk][kk] = d;
        const float di = 1.f / d;
        dinv[kk] = di;
#pragma unroll
        for (int r = 0; r < 16; ++r) if (r > kk) Dg[r][kk] *= di;
#pragma unroll
        for (int r = 0; r < 16; ++r) if (r > kk)
#pragma unroll
          for (int c2 = 0; c2 < 16; ++c2) if (c2 > kk && c2 <= r)
            Dg[r][c2] = fmaf(-Dg[r][kk], Dg[c2][kk], Dg[r][c2]);
      }
      if (tid == 0) {
#pragma unroll
        for (int kk = 0; kk < 16; ++kk) ldacc += logf(Dg[kk][kk]);
#pragma unroll
        for (int j = 0; j < 16; ++j) {
#pragma unroll
          for (int p4 = 0; p4 < 16; p4 += 4) {
            float4 q = {Dg[j][p4], Dg[j][p4+1], Dg[j][p4+2], Dg[j][p4+3]};
            EL4P(k0 + j, k0 + p4) = q;
          }
        }
      }
    }
    if (tid < R) {
      const int r = rbase + tid;
      float xr[16];
#pragma unroll
      for (int p4 = 0; p4 < 16; p4 += 4) {
        float4 q = EL4P(r, k0 + p4);
        xr[p4] = q.x; xr[p4+1] = q.y; xr[p4+2] = q.z; xr[p4+3] = q.w;
      }
#pragma unroll
      for (int j = 0; j < 16; ++j) {
        float s = xr[j];
#pragma unroll
        for (int p = 0; p < 16; ++p) if (p < j) s = fmaf(-Dg[j][p], xr[p], s);
        xr[j] = s * dinv[j];
      }
#pragma unroll
      for (int p4 = 0; p4 < 16; p4 += 4) {
        float4 q = {xr[p4], xr[p4+1], xr[p4+2], xr[p4+3]};
        EL4P(r, k0 + p4) = q;
      }
    }
    __syncthreads();
    if (R > 0) {
      const int Rt = R >> 2;
      const int T = (Rt * (Rt + 1)) >> 1;
      for (int idx = tid; idx < T; idx += 512) {
        int ti = (int)((sqrtf(8.f * (float)idx + 1.f) - 1.f) * 0.5f);
        while (((ti + 1) * (ti + 2)) / 2 <= idx) ++ti;
        while ((ti * (ti + 1)) / 2 > idx) --ti;
        const int tj = idx - (ti * (ti + 1)) / 2;
        const int i0 = rbase + (ti << 2), j0 = rbase + (tj << 2);
        float Li[4][16], Lj[4][16];
#pragma unroll
        for (int a = 0; a < 4; ++a)
#pragma unroll
          for (int p4 = 0; p4 < 16; p4 += 4) {
            float4 q = EL4P(i0 + a, k0 + p4);
            Li[a][p4] = q.x; Li[a][p4+1] = q.y; Li[a][p4+2] = q.z; Li[a][p4+3] = q.w;
          }
#pragma unroll
        for (int a = 0; a < 4; ++a)
#pragma unroll
          for (int p4 = 0; p4 < 16; p4 += 4) {
            float4 q = EL4P(j0 + a, k0 + p4);
            Lj[a][p4] = q.x; Lj[a][p4+1] = q.y; Lj[a][p4+2] = q.z; Lj[a][p4+3] = q.w;
          }
        float4 cc[4];
#pragma unroll
        for (int a = 0; a < 4; ++a) cc[a] = EL4P(i0 + a, j0);
#pragma unroll
        for (int p = 0; p < 16; ++p)
#pragma unroll
          for (int a = 0; a < 4; ++a) {
            cc[a].x = fmaf(-Li[a][p], Lj[0][p], cc[a].x);
            cc[a].y = fmaf(-Li[a][p], Lj[1][p], cc[a].y);
            cc[a].z = fmaf(-Li[a][p], Lj[2][p], cc[a].z);
            cc[a].w = fmaf(-Li[a][p], Lj[3][p], cc[a].w);
          }
#pragma unroll
        for (int a = 0; a < 4; ++a) EL4P(i0 + a, j0) = cc[a];
      }
    }
    __syncthreads();
  }
  for (int t = tid; t < 16384; t += 512) {
    const int i = t >> 7, j = t & 127;
    Lout[base + t] = (j <= i) ? ELX(i, j) : ELX(j, i);
  }
  if (tid < 128) Dinvb[(size_t)which * 8192 + bh * 128 + tid] = 1.f / ELX(tid, tid);
  if (tid == 0) ldbuf[which * 64 + bh] = 2.f * ldacc;
}

// ---------------------------------------------------------------------------
// Blocked batched cho_solve (NB=16), 512 threads.
// ---------------------------------------------------------------------------
__global__ __launch_bounds__(512) void solve5_kernel(
    const float* __restrict__ Lk, const float* __restrict__ Lo,
    const float* __restrict__ LTq, const float* __restrict__ LTk,
    const float* __restrict__ Dinvb,
    const float* __restrict__ PkTv, const float* __restrict__ PhiTy,
    const float* __restrict__ Cq, const float* __restrict__ Gk,
    float* __restrict__ Z1, float* __restrict__ Aoi,
    float* __restrict__ Z2, float* __restrict__ Wq2, float* __restrict__ Wk2)
{
  __shared__ alignas(16) float Xs[128][128];
  __shared__ alignas(16) float Lp[128][16];
  __shared__ float di[128];
  const int bh = blockIdx.x, which = blockIdx.y, tid = threadIdx.x;
  const float* Lsrc; const float* Bsrc; float* Out; int nr; int mat;
  if (which == 0)      { Lsrc = Lk;  Bsrc = PkTv;    Out = Z1;  nr = 64;  mat = 0; }
  else if (which == 1) { Lsrc = Lo;  Bsrc = nullptr; Out = Aoi; nr = 128; mat = 1; }
  else if (which == 2) { Lsrc = LTq; Bsrc = PhiTy;   Out = Z2;  nr = 64;  mat = 2; }
  else if (which == 3) { Lsrc = LTq; Bsrc = Cq;      Out = Wq2; nr = 128; mat = 2; }
  else                 { Lsrc = LTk; Bsrc = Gk;      Out = Wk2; nr = 128; mat = 3; }
  const size_t baseL = (size_t)bh * 16384;
  const size_t baseB = (size_t)bh * 128 * (size_t)nr;
  const int sh = (nr == 64) ? 6 : 7, mk2 = nr - 1;
  if (Bsrc) {
    for (int t = tid; t < 128 * nr; t += 512) Xs[t >> sh][t & mk2] = Bsrc[baseB + t];
  } else {
    for (int t = tid; t < 16384; t += 512)
      Xs[t >> 7][t & 127] = ((t >> 7) == (t & 127)) ? 1.f : 0.f;
  }
  if (tid < 128) di[tid] = Dinvb[(size_t)mat * 8192 + bh * 128 + tid];
  const int c0 = (nr == 128) ? ((tid & 31) << 2) : ((tid & 15) << 2);
  const int rg = (nr == 128) ? (tid >> 5) : (tid >> 4);
  const int rstride = (nr == 128) ? 16 : 32;
  __syncthreads();
  for (int kb = 0; kb < 8; ++kb) {
    const int k0 = kb << 4;
    const int nrow = 128 - k0;
    for (int t = tid; t < nrow * 4; t += 512) {
      const int pr = t >> 2, pc = (t & 3) << 2;
      *(float4*)&Lp[pr][pc] = *(const float4*)(Lsrc + baseL + (size_t)(k0 + pr) * 128 + k0 + pc);
    }
    __syncthreads();
    if (tid < nr) {
      float xb[16];
#pragma unroll
      for (int j = 0; j < 16; ++j) {
        float s = Xs[k0 + j][tid];
#pragma unroll
        for (int p = 0; p < 16; ++p) if (p < j) s = fmaf(-Lp[j][p], xb[p], s);
        xb[j] = s * di[k0 + j];
        Xs[k0 + j][tid] = xb[j];
      }
    }
    __syncthreads();
    if (k0 + 16 < 128) {
      float4 xb4[16];
#pragma unroll
      for (int p = 0; p < 16; ++p) xb4[p] = *(const float4*)&Xs[k0 + p][c0];
      for (int r = k0 + 16 + rg; r < 128; r += rstride) {
        float4 xv = *(const float4*)&Xs[r][c0];
#pragma unroll
        for (int p = 0; p < 16; ++p) {
          const float l = Lp[r - k0][p];
          xv.x = fmaf(-l, xb4[p].x, xv.x);
          xv.y = fmaf(-l, xb4[p].y, xv.y);
          xv.z = fmaf(-l, xb4[p].z, xv.z);
          xv.w = fmaf(-l, xb4[p].w, xv.w);
        }
        *(float4*)&Xs[r][c0] = xv;
      }
    }
    __syncthreads();
  }
  for (int kb = 7; kb >= 0; --kb) {
    const int k0 = kb << 4;
    const int nrow = k0 + 16;
    for (int t = tid; t < nrow * 4; t += 512) {
      const int pr = t >> 2, pc = (t & 3) << 2;
      *(float4*)&Lp[pr][pc] = *(const float4*)(Lsrc + baseL + (size_t)pr * 128 + k0 + pc);
    }
    __syncthreads();
    if (tid < nr) {
      float xb[16];
#pragma unroll
      for (int j = 15; j >= 0; --j) {
        float s = Xs[k0 + j][tid];
#pragma unroll
        for (int p = 0; p < 16; ++p) if (p > j) s = fmaf(-Lp[k0 + j][p], xb[p], s);
        xb[j] = s * di[k0 + j];
        Xs[k0 + j][tid] = xb[j];
      }
    }
    __syncthreads();
    if (k0 > 0) {
      float4 xb4[16];
#pragma unroll
      for (int p = 0; p < 16; ++p) xb4[p] = *(const float4*)&Xs[k0 + p][c0];
      for (int r = rg; r < k0; r += rstride) {
        float4 xv = *(const float4*)&Xs[r][c0];
#pragma unroll
        for (int p = 0; p < 16; ++p) {
          const float l = Lp[r][p];
          xv.x = fmaf(-l, xb4[p].x, xv.x);
          xv.y = fmaf(-l, xb4[p].y, xv.y);
          xv.z = fmaf(-l, xb4[p].z, xv.z);
          xv.w = fmaf(-l, xb4[p].w, xv.w);
        }
        *(float4*)&Xs[r][c0] = xv;
      }
    }
    __syncthreads();
  }
  for (int t = tid; t < 128 * nr; t += 512) Out[baseB + t] = Xs[t >> sh][t & mk2];
}

// ---------------------------------------------------------------------------
// mid = Z1 - 0.01 * Aoi @ Z1   (Aoi symmetric)
// ---------------------------------------------------------------------------
__global__ __launch_bounds__(256) void mid_kernel(
    const float* __restrict__ Aoi, const float* __restrict__ Z1,
    float* __restrict__ midb)
{
  __shared__ alignas(16) float Ao[128][128];
  __shared__ alignas(16) float Z[128][64];
  const int bh = blockIdx.x, tid = threadIdx.x;
  const size_t bM = (size_t)bh * 16384, bD = (size_t)bh * 8192;
  for (int t4 = tid; t4 < 4096; t4 += 256) {
    const int r = t4 >> 5, c4 = (t4 & 31) << 2;
    *(float4*)&Ao[r][c4] = *(const float4*)(Aoi + bM + (size_t)r*128 + c4);
  }
  for (int t4 = tid; t4 < 2048; t4 += 256) {
    const int r = t4 >> 4, c4 = (t4 & 15) << 2;
    *(float4*)&Z[r][c4] = *(const float4*)(Z1 + bD + (size_t)r*64 + c4);
  }
  __syncthreads();
  const int ty = tid >> 4, tx = tid & 15;
  float acc[8][4];
#pragma unroll
  for (int i = 0; i < 8; ++i)
#pragma unroll
    for (int j = 0; j < 4; ++j) acc[i][j] = 0.f;
  for (int kk = 0; kk < 128; ++kk) {
    float4 a0 = *(const float4*)&Ao[kk][ty*8];
    float4 a1 = *(const float4*)&Ao[kk][ty*8+4];
    float4 bv = *(const float4*)&Z[kk][tx*4];
    float a[8] = {a0.x, a0.y, a0.z, a0.w, a1.x, a1.y, a1.z, a1.w};
    float b[4] = {bv.x, bv.y, bv.z, bv.w};
#pragma unroll
    for (int i = 0; i < 8; ++i)
#pragma unroll
      for (int j = 0; j < 4; ++j) acc[i][j] = fmaf(a[i], b[j], acc[i][j]);
  }
#pragma unroll
  for (int i = 0; i < 8; ++i) {
    const int r = ty*8 + i, c = tx*4;
    float4 o;
    o.x = Z[r][c+0] - 0.01f*acc[i][0];
    o.y = Z[r][c+1] - 0.01f*acc[i][1];
    o.z = Z[r][c+2] - 0.01f*acc[i][2];
    o.w = Z[r][c+3] - 0.01f*acc[i][3];
    *(float4*)(midb + bD + (size_t)r*64 + c) = o;
  }
}

// ---------------------------------------------------------------------------
// Pq = Cq @ Wq2 ; Pk = Gk @ Wk2   (A operand symmetric)
// ---------------------------------------------------------------------------
__global__ __launch_bounds__(256) void pmat_kernel(
    const float* __restrict__ Cq, const float* __restrict__ Wq2,
    const float* __restrict__ Gk, const float* __restrict__ Wk2,
    float* __restrict__ Pq, float* __restrict__ Pk)
{
  __shared__ alignas(16) float Am[128][128];
  __shared__ alignas(16) float Bm[128][128];
  const int bh = blockIdx.x, which = blockIdx.y, tid = threadIdx.x;
  const float* Ap = which ? Gk : Cq;
  const float* Bp = which ? Wk2 : Wq2;
  float* Op = which ? Pk : Pq;
  const size_t base = (size_t)bh * 16384;
  for (int t4 = tid; t4 < 4096; t4 += 256) {
    const int r = t4 >> 5, c4 = (t4 & 31) << 2;
    *(float4*)&Am[r][c4] = *(const float4*)(Ap + base + (size_t)r*128 + c4);
    *(float4*)&Bm[r][c4] = *(const float4*)(Bp + base + (size_t)r*128 + c4);
  }
  __syncthreads();
  const int ty = tid >> 4, tx = tid & 15;
  float acc[8][8];
#pragma unroll
  for (int i = 0; i < 8; ++i)
#pragma unroll
    for (int j = 0; j < 8; ++j) acc[i][j] = 0.f;
  for (int kk = 0; kk < 128; ++kk) {
    float4 av0 = *(const float4*)&Am[kk][ty*8];
    float4 av1 = *(const float4*)&Am[kk][ty*8+4];
    float4 bv0 = *(const float4*)&Bm[kk][tx*8];
    float4 bv1 = *(const float4*)&Bm[kk][tx*8+4];
    float a[8] = {av0.x, av0.y, av0.z, av0.w, av1.x, av1.y, av1.z, av1.w};
    float b[8] = {bv0.x, bv0.y, bv0.z, bv0.w, bv1.x, bv1.y, bv1.z, bv1.w};
#pragma unroll
    for (int i = 0; i < 8; ++i)
#pragma unroll
      for (int j = 0; j < 8; ++j) acc[i][j] = fmaf(a[i], b[j], acc[i][j]);
  }
#pragma unroll
  for (int i = 0; i < 8; ++i)
#pragma unroll
    for (int j = 0; j < 8; j += 4) {
      float4 o = {acc[i][j], acc[i][j+1], acc[i][j+2], acc[i][j+3]};
      *(float4*)(Op + base + (size_t)(ty*8+i)*128 + tx*8 + j) = o;
    }
}

// ---------------------------------------------------------------------------
__global__ __launch_bounds__(256) void scalars_kernel(
    const float* __restrict__ Aoi, const float* __restrict__ Cq, const float* __restrict__ Gk,
    const float* __restrict__ Pq, const float* __restrict__ Pk, const float* __restrict__ Wk2,
    const float* __restrict__ PhiTy, const float* __restrict__ Z2,
    const float* __restrict__ yyp, const float* __restrict__ ldb,
    float* __restrict__ regp)
{
  const int bh = blockIdx.x, tid = threadIdx.x;
  const size_t b0 = (size_t)bh * 16384, b1 = (size_t)bh * 8192;
  double aoCq=0, aoGk=0, aoPq=0, aoPk=0, wkGk=0, trCq=0, trGk=0, trPq=0, trPk=0, s1=0;
  for (int t = tid; t < 16384; t += 256) {
    const double ao = Aoi[b0+t], cq = Cq[b0+t], gk = Gk[b0+t];
    const double pq = Pq[b0+t], pk = Pk[b0+t], wk = Wk2[b0+t];
    aoCq += ao*cq; aoGk += ao*gk; aoPq += ao*pq; aoPk += ao*pk; wkGk += wk*gk;
    if (t % 129 == 0) { trCq += cq; trGk += gk; trPq += pq; trPk += pk; }
  }
  for (int t = tid; t < 8192; t += 256) s1 += (double)PhiTy[b1+t] * (double)Z2[b1+t];
  __shared__ double red[256];
  double vals[10] = {aoCq, aoGk, aoPq, aoPk, wkGk, trCq, trGk, trPq, trPk, s1};
  double tot[10];
  for (int vv = 0; vv < 10; ++vv) {
    red[tid] = vals[vv];
    __syncthreads();
    for (int st = 128; st > 0; st >>= 1) {
      if (tid < st) red[tid] += red[tid+st];
      __syncthreads();
    }
    tot[vv] = red[0];
    __syncthreads();
  }
  if (tid == 0) {
    const double D = 64.0, Nd = 2048.0;
    const double ldAo = ldb[64 + bh], ldTq = ldb[128 + bh], ldTk = ldb[192 + bh];
    double yv = 0.0;
    for (int c = 0; c < 8; ++c) yv += (double)yyp[c * 64 + bh];
    const double cst  = Nd * log(2.0 * 3.14159265358979323846);
    const double leps = Nd * log(0.002);
    const double datq = 500.0*yv - 2500.0*tot[9];
    const double modq = D*(500.0*tot[5] - 2500.0*tot[7] - 0.01*(500.0*tot[0] - 2500.0*tot[2]));
    const double ldq  = leps + ldTq - ldAo;
    const double LBq  = -0.5*(datq + modq + ldq + cst);
    const double datk = D*(500.0*tot[6] - 2500.0*tot[4]);
    const double modk = D*(500.0*tot[6] - 2500.0*tot[8] - 0.01*(500.0*tot[1] - 2500.0*tot[3]));
    const double ldk  = leps + ldTk - ldAo;
    const double LBk  = -0.5*(datk + modk + ldk + cst);
    regp[bh] = (float)(-(LBq + LBk) / 64.0);
  }
}

__global__ void regfinal_kernel(const float* __restrict__ regp, float* __restrict__ outp)
{
  __shared__ float red[64];
  const int tid = threadIdx.x;
  red[tid] = regp[tid];
  __syncthreads();
  for (int st = 32; st > 0; st >>= 1) {
    if (tid < st) red[tid] += red[tid+st];
    __syncthreads();
  }
  if (tid == 0) outp[0] = red[0];
}

// ---------------------------------------------------------------------------
// y = Phi_q @ mid -> emitted as bf16 hi/lo natural layout (feeds gemm_out B).
// Phi_q read from PT3 packed layout.
// ---------------------------------------------------------------------------
__global__ __launch_bounds__(256) void y_kernel(
    const unsigned short* __restrict__ PThi, const unsigned short* __restrict__ PTlo,
    const float* __restrict__ midb,
    unsigned short* __restrict__ Yhi, unsigned short* __restrict__ Ylo)
{
  __shared__ float Ps[128][129];   // Ps[n][m], padded
  __shared__ alignas(16) float Ms[128][64];
  const int blk = blockIdx.x;
  const int bh = blk >> 4, nt = blk & 15;
  const int b = bh >> 3, h = bh & 7;
  const int n0 = nt << 7;
  const int tid = threadIdx.x;
  for (int t = tid; t < 4096; t += 256) {
    const int m = t & 127, npr = t >> 7;   // npr 0..31 covers 128 n
    const size_t idx = ((size_t)((n0 >> 2) + npr) * 8192 + bh * 128 + m) << 2;
    ushort4 h4 = *(const ushort4*)(PThi + idx);
    ushort4 l4 = *(const ushort4*)(PTlo + idx);
    Ps[npr*4+0][m] = bf2f(h4.x) + bf2f(l4.x);
    Ps[npr*4+1][m] = bf2f(h4.y) + bf2f(l4.y);
    Ps[npr*4+2][m] = bf2f(h4.z) + bf2f(l4.z);
    Ps[npr*4+3][m] = bf2f(h4.w) + bf2f(l4.w);
  }
  for (int t4 = tid; t4 < 2048; t4 += 256) {
    const int r = t4 >> 4, c4 = (t4 & 15) << 2;
    *(float4*)&Ms[r][c4] = *(const float4*)(midb + (size_t)bh*8192 + (size_t)r*64 + c4);
  }
  __syncthreads();
  const int ty = tid >> 4, tx = tid & 15;
  float acc[8][4];
#pragma unroll
  for (int i = 0; i < 8; ++i)
#pragma unroll
    for (int j = 0; j < 4; ++j) acc[i][j] = 0.f;
  for (int kk = 0; kk < 128; ++kk) {
    float4 bv = *(const float4*)&Ms[kk][tx*4];
    float b4[4] = {bv.x, bv.y, bv.z, bv.w};
#pragma unroll
    for (int i = 0; i < 8; ++i) {
      const float a = Ps[ty*8+i][kk];
      acc[i][0] = fmaf(a, b4[0], acc[i][0]);
      acc[i][1] = fmaf(a, b4[1], acc[i][1]);
      acc[i][2] = fmaf(a, b4[2], acc[i][2]);
      acc[i][3] = fmaf(a, b4[3], acc[i][3]);
    }
  }
#pragma unroll
  for (int i = 0; i < 8; ++i) {
    const size_t addr = ((size_t)(b*N_) + n0 + ty*8 + i)*512 + h*64 + tx*4;
    ushort4 hv, lv;
    hv.x = f2bf(acc[i][0]); lv.x = f2bf(acc[i][0] - bf2f(hv.x));
    hv.y = f2bf(acc[i][1]); lv.y = f2bf(acc[i][1] - bf2f(hv.y));
    hv.z = f2bf(acc[i][2]); lv.z = f2bf(acc[i][2] - bf2f(hv.z));
    hv.w = f2bf(acc[i][3]); lv.w = f2bf(acc[i][3] - bf2f(hv.w));
    *(ushort4*)(Yhi + addr) = hv;
    *(ushort4*)(Ylo + addr) = lv;
  }
}

// ---------------------------------------------------------------------------
extern "C" void kernel_launch(void* const* d_in, const int* in_sizes, int n_in,
                              void* d_out, int out_size, void* d_ws, size_t ws_size,
                              hipStream_t stream)
{
  const float* x     = (const float*)d_in[0];
  const float* mask  = (const float*)d_in[1];
  const float* Wq    = (const float*)d_in[2];
  const float* bq    = (const float*)d_in[3];
  const float* Wk    = (const float*)d_in[4];
  const float* bk    = (const float*)d_in[5];
  const float* Wv    = (const float*)d_in[6];
  const float* bv    = (const float*)d_in[7];
  const float* Wx0   = (const float*)d_in[8];
  const float* bx0   = (const float*)d_in[9];
  const float* Wo    = (const float*)d_in[10];
  const float* bo    = (const float*)d_in[11];
  const float* omega = (const float*)d_in[12];
  const float* brff  = (const float*)d_in[13];
  float* outp = (float*)d_out;

  float* W_ = (float*)d_ws;
  size_t off = 0;
  auto take = [&](size_t n) -> float* { float* p = W_ + off; off += n; return p; };
  const size_t SZ_BNH = (size_t)8*2048*512;    // 8,388,608
  const size_t SZ_MM  = (size_t)64*128*128;    // 1,048,576
  const size_t SZ_MD  = (size_t)64*128*64;     //   524,288

  unsigned short* Xhi  = (unsigned short*)take(SZ_BNH/2);
  unsigned short* Xlo  = (unsigned short*)take(SZ_BNH/2);
  unsigned short* PThi = (unsigned short*)take(SZ_BNH);
  unsigned short* PTlo = (unsigned short*)take(SZ_BNH);
  unsigned short* VThi = (unsigned short*)take(SZ_BNH/2);
  unsigned short* VTlo = (unsigned short*)take(SZ_BNH/2);
  unsigned short* WOmH = (unsigned short*)take(786432);
  unsigned short* WOmL = (unsigned short*)take(786432);
  float* bias2 = take(3072);
  unsigned short* WvH = (unsigned short*)take(131072);
  unsigned short* WvL = (unsigned short*)take(131072);
  unsigned short* WoH = (unsigned short*)take(131072);
  unsigned short* WoL = (unsigned short*)take(131072);
  float* Gk   = take(SZ_MM);
  float* Go   = take(SZ_MM);
  float* Cq   = take(SZ_MM);
  float* Lk   = take(SZ_MM);
  float* Lo   = take(SZ_MM);
  float* LTq  = take(SZ_MM);
  float* LTk  = take(SZ_MM);
  float* Aoi  = take(SZ_MM);
  float* Wq2  = take(SZ_MM);
  float* Wk2  = take(SZ_MM);
  float* Pq   = take(SZ_MM);
  float* Pk   = take(SZ_MM);
  float* PkTv = take(SZ_MD);
  float* PhiTy= take(SZ_MD);
  float* Z1   = take(SZ_MD);
  float* Z2   = take(SZ_MD);
  float* midb = take(SZ_MD);
  float* GPart= take(4*SZ_MM);
  float* PPart= take(4*SZ_MD);
  float* Dinv = take(4*64*128);
  float* yyp  = take(512);
  float* ldb  = take(256);
  float* regp = take(64);
  (void)ws_size; (void)in_sizes; (void)n_in; (void)out_size;

  // input prep
  split_kernel<<<8192, 256, 0, stream>>>(x, Xhi, Xlo, (int)SZ_BNH);
  split_kernel<<<256, 256, 0, stream>>>(Wv, WvH, WvL, 262144);
  split_kernel<<<256, 256, 0, stream>>>(Wo, WoH, WoL, 262144);
  womb_kernel<<<3072, 256, 0, stream>>>(Wq, Wk, Wx0, bq, bk, bx0, omega, brff,
                                        WOmH, WOmL, bias2);
  // v path -> VT3, yy
  gemm_vt<<<512, 256, 0, stream>>>(Xhi, Xlo, WvH, WvL, bv, mask, VThi, VTlo);
  yy_vt<<<dim3(64, 8), 256, 0, stream>>>(VThi, VTlo, yyp);
  // x0 path -> Go   (path index 2 in WOm)
  gemm_rff<<<1024, 256, 0, stream>>>(Xhi, Xlo, WOmH + 2*524288, WOmL + 2*524288,
                                     bias2 + 2048, mask, PThi, PTlo);
  gram_ptv<<<dim3(64, 4), 256, 0, stream>>>(PThi, PTlo, VThi, VTlo, GPart, PPart, 0);
  reduce4_kernel<<<4096, 256, 0, stream>>>(GPart, Go, 1048576, (size_t)1048576);
  // k path -> Gk, PkTv  (path 1)
  gemm_rff<<<1024, 256, 0, stream>>>(Xhi, Xlo, WOmH + 1*524288, WOmL + 1*524288,
                                     bias2 + 1024, mask, PThi, PTlo);
  gram_ptv<<<dim3(64, 4), 256, 0, stream>>>(PThi, PTlo, VThi, VTlo, GPart, PPart, 1);
  reduce4_kernel<<<4096, 256, 0, stream>>>(GPart, Gk, 1048576, (size_t)1048576);
  reduce4_kernel<<<2048, 256, 0, stream>>>(PPart, PkTv, 524288, (size_t)524288);
  // q path -> Cq, PhiTy  (path 0; PT3 stays live for y_kernel)
  gemm_rff<<<1024, 256, 0, stream>>>(Xhi, Xlo, WOmH, WOmL,
                                     bias2, mask, PThi, PTlo);
  gram_ptv<<<dim3(64, 4), 256, 0, stream>>>(PThi, PTlo, VThi, VTlo, GPart, PPart, 1);
  reduce4_kernel<<<4096, 256, 0, stream>>>(GPart, Cq, 1048576, (size_t)1048576);
  reduce4_kernel<<<2048, 256, 0, stream>>>(PPart, PhiTy, 524288, (size_t)524288);
  // batched linear algebra
  chol4_kernel<<<dim3(64, 4), 512, 0, stream>>>(Gk, Go, Cq, Lk, Lo, LTq, LTk, ldb, Dinv);
  solve5_kernel<<<dim3(64, 5), 512, 0, stream>>>(Lk, Lo, LTq, LTk, Dinv, PkTv, PhiTy, Cq, Gk,
                                                 Z1, Aoi, Z2, Wq2, Wk2);
  mid_kernel<<<64, 256, 0, stream>>>(Aoi, Z1, midb);
  pmat_kernel<<<dim3(64, 2), 256, 0, stream>>>(Cq, Wq2, Gk, Wk2, Pq, Pk);
  scalars_kernel<<<64, 256, 0, stream>>>(Aoi, Cq, Gk, Pq, Pk, Wk2, PhiTy, Z2, yyp, ldb, regp);
  regfinal_kernel<<<1, 64, 0, stream>>>(regp, outp + SZ_BNH);
  // output path: y -> bf16 hi/lo natural layout (reusing Xhi/Xlo), then
  // operand-swapped projection (A=Wo rows=cols, B=y rows=rows).
  y_kernel<<<1024, 256, 0, stream>>>(PThi, PTlo, midb, Xhi, Xlo);
  gemm_out<<<512, 256, 0, stream>>>(WoH, WoL, Xhi, Xlo, bo, outp);
}

// Round 14
// 695.065 us; speedup vs baseline: 1.0996x; 1.0996x over previous
//
#include <hip/hip_runtime.h>
#include <math.h>

// Problem constants
#define B_ 8
#define N_ 2048
#define HD_ 512
#define H_ 8
#define M_ 128
#define VD_ 64
// LAM = 0.01, EPS = 0.002 ; LAM/EPS = 5 ; 1/EPS = 500 ; 1/(100*EPS^2) = 2500
// Workspace: ~57.2M floats (~229 MB) — under the 256MiB d_ws.
//
// Packed bf16 tensor layout ("PT3"): linear = (npack*NR + R)*4 + e, n=npack*4+e.
// PT: NR=8192, R=bh*128+m. VT: NR=4096, R=bh*64+d.
//
// ROUND 14: revert to round-12 build (best known: 695us, chol4/solve5 at
// 256 threads). Round-13's 512-thread variant regressed chol4 80->134us:
// critical phases use <=128 threads, so extra waves only added barrier
// convergence cost at unchanged 1 block/CU.

typedef __attribute__((ext_vector_type(8))) short short8v;   // 8 bf16 (4 VGPRs)
typedef __attribute__((ext_vector_type(4))) float f32x4;

__device__ __forceinline__ unsigned short f2bf(float f) {
  unsigned u = __float_as_uint(f);
  u += 0x7FFF + ((u >> 16) & 1);   // round-to-nearest-even
  return (unsigned short)(u >> 16);
}
__device__ __forceinline__ float bf2f(unsigned short h) {
  return __uint_as_float(((unsigned)h) << 16);
}

// async global->LDS, 16B per lane; lptr must be wave-uniform base (lane*16 added by HW)
__device__ __forceinline__ void gload16(const unsigned short* g, unsigned short* l) {
  __builtin_amdgcn_global_load_lds(
      (const __attribute__((address_space(1))) unsigned int*)g,
      (__attribute__((address_space(3))) unsigned int*)l, 16, 0, 0);
}

// ---------------------------------------------------------------------------
// Split fp32 -> (hi, lo) bf16 pair.
// ---------------------------------------------------------------------------
__global__ __launch_bounds__(256) void split_kernel(
    const float* __restrict__ in, unsigned short* __restrict__ hi,
    unsigned short* __restrict__ lo, int n)
{
  const int i = (blockIdx.x * 256 + threadIdx.x) << 2;
  if (i >= n) return;
  float4 v = *(const float4*)(in + i);
  ushort4 h, l;
  h.x = f2bf(v.x); l.x = f2bf(v.x - bf2f(h.x));
  h.y = f2bf(v.y); l.y = f2bf(v.y - bf2f(h.y));
  h.z = f2bf(v.z); l.z = f2bf(v.z - bf2f(h.z));
  h.w = f2bf(v.w); l.w = f2bf(v.w - bf2f(h.w));
  *(ushort4*)(hi + i) = h;
  *(ushort4*)(lo + i) = l;
}

// ---------------------------------------------------------------------------
// Combined RFF weights: WOmT[path][hm][p] = sum_d W[h*64+d][p]*omega[d][m]
// ---------------------------------------------------------------------------
__global__ __launch_bounds__(256) void womb_kernel(
    const float* __restrict__ Wq, const float* __restrict__ Wk, const float* __restrict__ Wx0,
    const float* __restrict__ bq, const float* __restrict__ bk, const float* __restrict__ bx0,
    const float* __restrict__ omega, const float* __restrict__ brff,
    unsigned short* __restrict__ WOmH, unsigned short* __restrict__ WOmL,
    float* __restrict__ bias2)
{
  const int blk = blockIdx.x, tid = threadIdx.x;
  const int path = blk >> 10, hm = blk & 1023;
  const int h = hm >> 7, m = hm & 127;
  const float* W  = (path == 0) ? Wq : (path == 1) ? Wk : Wx0;
  const float* bv = (path == 0) ? bq : (path == 1) ? bk : bx0;
  __shared__ float om[64];
  if (tid < 64) om[tid] = omega[tid * 128 + m];
  __syncthreads();
  for (int c = tid; c < 512; c += 256) {
    float s = 0.f;
#pragma unroll 8
    for (int d = 0; d < 64; ++d) s = fmaf(W[(h * 64 + d) * 512 + c], om[d], s);
    const unsigned short sh = f2bf(s);
    const size_t o = (size_t)(path * 1024 + hm) * 512 + c;
    WOmH[o] = sh;
    WOmL[o] = f2bf(s - bf2f(sh));
  }
  if (tid == 0) {
    float s = 0.f;
    for (int d = 0; d < 64; ++d) s = fmaf(bv[h * 64 + d], om[d], s);
    bias2[path * 1024 + hm] = s + brff[m];
  }
}

// ---------------------------------------------------------------------------
// bf16x3 MFMA GEMM core (128x128 tile, 256 thr, K=512), gload_lds staging.
// ---------------------------------------------------------------------------
#define LDP 32
#define GEMM_PROLOGUE(NCOLBITS)                                              \
  __shared__ unsigned short Ah[128 * LDP], Al[128 * LDP];                    \
  __shared__ unsigned short Bh[128 * LDP], Bl[128 * LDP];                    \
  const int tid = threadIdx.x;                                               \
  const int bx = blockIdx.x & ((1 << (NCOLBITS)) - 1);                       \
  const int by = blockIdx.x >> (NCOLBITS);                                   \
  const int row0 = by << 7, col0 = bx << 7;                                  \
  const int lane = tid & 63, wave = tid >> 6;                                \
  const int wr = wave >> 1, wc = wave & 1;                                   \
  const int fr = lane & 15, fk = (lane >> 4) << 3;                           \
  f32x4 acc[4][4];                                                           \
  _Pragma("unroll") for (int i = 0; i < 4; ++i)                              \
  _Pragma("unroll") for (int j = 0; j < 4; ++j)                              \
      acc[i][j] = (f32x4){0.f, 0.f, 0.f, 0.f};                               \
  const int srow = tid >> 2;                                                 \
  const int sch = (tid & 3) << 3;                                            \
  const size_t ga = (size_t)(row0 + srow) * 512 + sch;                       \
  const size_t gb = (size_t)(col0 + srow) * 512 + sch;                       \
  const int ldw = wave * 512;   /* wave-uniform ushort offset (1KB/wave) */

#define GEMM_KLOOP                                                           \
  for (int kt = 0; kt < 16; ++kt) {                                          \
    const int kko = kt * 32;                                                 \
    __syncthreads();                                                         \
    gload16(Ahi + ga + kko,                    Ah + ldw);                    \
    gload16(Ahi + ga + (size_t)64 * 512 + kko, Ah + 64 * LDP + ldw);         \
    gload16(Alo + ga + kko,                    Al + ldw);                    \
    gload16(Alo + ga + (size_t)64 * 512 + kko, Al + 64 * LDP + ldw);         \
    gload16(Bhi + gb + kko,                    Bh + ldw);                    \
    gload16(Bhi + gb + (size_t)64 * 512 + kko, Bh + 64 * LDP + ldw);         \
    gload16(Blo + gb + kko,                    Bl + ldw);                    \
    gload16(Blo + gb + (size_t)64 * 512 + kko, Bl + 64 * LDP + ldw);         \
    __syncthreads();                                                         \
    short8v a_hi[4], a_lo[4];                                                \
    _Pragma("unroll") for (int i = 0; i < 4; ++i) {                          \
      const int ar = (wr * 64 + i * 16 + fr) * LDP + fk;                     \
      a_hi[i] = *(const short8v*)&Ah[ar];                                    \
      a_lo[i] = *(const short8v*)&Al[ar];                                    \
    }                                                                        \
    _Pragma("unroll") for (int j = 0; j < 4; ++j) {                          \
      const int br = (wc * 64 + j * 16 + fr) * LDP + fk;                     \
      short8v b_hi = *(const short8v*)&Bh[br];                               \
      short8v b_lo = *(const short8v*)&Bl[br];                               \
      _Pragma("unroll") for (int i = 0; i < 4; ++i) {                        \
        acc[i][j] = __builtin_amdgcn_mfma_f32_16x16x32_bf16(a_hi[i], b_hi, acc[i][j], 0, 0, 0); \
        acc[i][j] = __builtin_amdgcn_mfma_f32_16x16x32_bf16(a_hi[i], b_lo, acc[i][j], 0, 0, 0); \
        acc[i][j] = __builtin_amdgcn_mfma_f32_16x16x32_bf16(a_lo[i], b_hi, acc[i][j], 0, 0, 0); \
      }                                                                      \
    }                                                                        \
  }

// Direct packed-layout store: one ushort4 per (i,j) per lane; consecutive
// lanes contiguous -> 4 x 128B dense segments per wave store instruction.
#define PT3_WRITE(HIbuf, LObuf, RBASE, NR)                                   \
  {                                                                          \
    const int hi4_ = lane >> 4;                                              \
    _Pragma("unroll") for (int j = 0; j < 4; ++j) {                          \
      const int rr = (RBASE) + wc * 64 + j * 16 + fr;                        \
      _Pragma("unroll") for (int i = 0; i < 4; ++i) {                        \
        const int npack = (n0t >> 2) + wr * 16 + hi4_ + i * 4;               \
        ushort4 hv, lv;                                                      \
        hv.x = f2bf(acc[i][j][0]); lv.x = f2bf(acc[i][j][0] - bf2f(hv.x));   \
        hv.y = f2bf(acc[i][j][1]); lv.y = f2bf(acc[i][j][1] - bf2f(hv.y));   \
        hv.z = f2bf(acc[i][j][2]); lv.z = f2bf(acc[i][j][2] - bf2f(hv.z));   \
        hv.w = f2bf(acc[i][j][3]); lv.w = f2bf(acc[i][j][3] - bf2f(hv.w));   \
        const size_t idx = ((size_t)npack * (NR) + rr) << 2;                 \
        *(ushort4*)(HIbuf + idx) = hv;                                       \
        *(ushort4*)(LObuf + idx) = lv;                                       \
      }                                                                      \
    }                                                                        \
  }

// ---------------------------------------------------------------------------
// Final projection (operand-swapped): A = Wo (rows = output cols, 512),
// B = y (rows = output rows, 16384). Lane owns 4 consecutive output cols
// -> float4 stores. grid 512, NCOLBITS=7.
// ---------------------------------------------------------------------------
__global__ __launch_bounds__(256, 1) void gemm_out(
    const unsigned short* __restrict__ Ahi, const unsigned short* __restrict__ Alo,
    const unsigned short* __restrict__ Bhi, const unsigned short* __restrict__ Blo,
    const float* __restrict__ bias, float* __restrict__ Y)
{
  GEMM_PROLOGUE(7)
  GEMM_KLOOP
  const int hi4_ = lane >> 4;
#pragma unroll
  for (int j = 0; j < 4; ++j) {
    const int r = col0 + wc * 64 + j * 16 + fr;
#pragma unroll
    for (int i = 0; i < 4; ++i) {
      const int c0 = row0 + wr * 64 + i * 16 + (hi4_ << 2);
      const float4 bc4 = *(const float4*)(bias + c0);
      float4 o;
      o.x = acc[i][j][0] + bc4.x;
      o.y = acc[i][j][1] + bc4.y;
      o.z = acc[i][j][2] + bc4.z;
      o.w = acc[i][j][3] + bc4.w;
      *(float4*)(Y + (size_t)r * 512 + c0) = o;
    }
  }
}

// ---------------------------------------------------------------------------
// V GEMM: emits VT3 packed (NR=4096, R=b*512+col), v=(acc+bias)*mask[row].
// ---------------------------------------------------------------------------
__global__ __launch_bounds__(256, 1) void gemm_vt(
    const unsigned short* __restrict__ Ahi, const unsigned short* __restrict__ Alo,
    const unsigned short* __restrict__ Bhi, const unsigned short* __restrict__ Blo,
    const float* __restrict__ bias, const float* __restrict__ mask,
    unsigned short* __restrict__ VThi, unsigned short* __restrict__ VTlo)
{
  GEMM_PROLOGUE(2)
  GEMM_KLOOP
  const int b = row0 >> 11;
  const int n0t = row0 & 2047;
  const int hi4 = lane >> 4;
  float mk[4][4];
#pragma unroll
  for (int i = 0; i < 4; ++i)
#pragma unroll
    for (int r = 0; r < 4; ++r)
      mk[i][r] = mask[b * 2048 + n0t + wr * 64 + (hi4 << 2) + i * 16 + r];
#pragma unroll
  for (int j = 0; j < 4; ++j) {
    const float bc = bias[col0 + wc * 64 + j * 16 + fr];
#pragma unroll
    for (int i = 0; i < 4; ++i)
#pragma unroll
      for (int r = 0; r < 4; ++r)
        acc[i][j][r] = (acc[i][j][r] + bc) * mk[i][r];
  }
  PT3_WRITE(VThi, VTlo, b * 512 + col0, 4096)
}

// ---------------------------------------------------------------------------
// Fused head-GEMM + RFF: Phi = 0.125*__cosf(x@WOmT^T + bias2)*mask.
// Emits PT3 packed (NR=8192, R=bh*128+m). grid 1024: 8 head-tiles x 128 rows.
// ---------------------------------------------------------------------------
__global__ __launch_bounds__(256, 1) void gemm_rff(
    const unsigned short* __restrict__ Ahi, const unsigned short* __restrict__ Alo,
    const unsigned short* __restrict__ Bhi, const unsigned short* __restrict__ Blo,
    const float* __restrict__ bias2, const float* __restrict__ mask,
    unsigned short* __restrict__ PThi, unsigned short* __restrict__ PTlo)
{
  GEMM_PROLOGUE(3)
  GEMM_KLOOP
  const int b = row0 >> 11;
  const int n0t = row0 & 2047;
  const int bh = b * 8 + bx;     // col tile == head
  const int hi4 = lane >> 4;
  float mk[4][4];
#pragma unroll
  for (int i = 0; i < 4; ++i)
#pragma unroll
    for (int r = 0; r < 4; ++r)
      mk[i][r] = mask[b * 2048 + n0t + wr * 64 + (hi4 << 2) + i * 16 + r];
#pragma unroll
  for (int j = 0; j < 4; ++j) {
    const float bb = bias2[col0 + wc * 64 + j * 16 + fr];
#pragma unroll
    for (int i = 0; i < 4; ++i)
#pragma unroll
      for (int r = 0; r < 4; ++r)
        acc[i][j][r] = 0.125f * __cosf(acc[i][j][r] + bb) * mk[i][r];
  }
  PT3_WRITE(PThi, PTlo, bh * 128, 8192)
}

// ---------------------------------------------------------------------------
// Combined Gram + PhiT*V partials via MFMA (bf16x3), PT3/VT3 inputs.
// ---------------------------------------------------------------------------
#define GPD 72
__global__ __launch_bounds__(256) void gram_ptv(
    const unsigned short* __restrict__ PThi, const unsigned short* __restrict__ PTlo,
    const unsigned short* __restrict__ VThi, const unsigned short* __restrict__ VTlo,
    float* __restrict__ GPart, float* __restrict__ PPart, int withV)
{
  __shared__ unsigned short Ath[128 * GPD], Atl[128 * GPD];
  __shared__ unsigned short Vh[64 * GPD], Vl[64 * GPD];
  const int bh = blockIdx.x, sp = blockIdx.y, tid = threadIdx.x;
  const int lane = tid & 63, wave = tid >> 6;
  const int wr = wave >> 1, wc = wave & 1;
  const int fr = lane & 15, fk = (lane >> 4) << 3;
  const int skipj = (!withV && wc == 1);
  f32x4 acc[4][6];
#pragma unroll
  for (int i = 0; i < 4; ++i)
#pragma unroll
    for (int j = 0; j < 6; ++j) acc[i][j] = (f32x4){0.f, 0.f, 0.f, 0.f};
  const int sm = tid & 127, sph = tid >> 7;   // PT staging: m, half
  const int sd = tid & 63, spv = tid >> 6;    // V staging: d, quarter
  for (int n0 = sp * 512; n0 < sp * 512 + 512; n0 += 64) {
    __syncthreads();
#pragma unroll
    for (int s = 0; s < 8; ++s) {
      const int npr = sph * 8 + s;
      const size_t idx = ((size_t)((n0 >> 2) + npr) * 8192 + bh * 128 + sm) << 2;
      *(ushort4*)&Ath[sm * GPD + npr * 4] = *(const ushort4*)(PThi + idx);
      *(ushort4*)&Atl[sm * GPD + npr * 4] = *(const ushort4*)(PTlo + idx);
    }
    if (withV) {
#pragma unroll
      for (int s = 0; s < 4; ++s) {
        const int npr = spv * 4 + s;
        const size_t idx = ((size_t)((n0 >> 2) + npr) * 4096 + bh * 64 + sd) << 2;
        *(ushort4*)&Vh[sd * GPD + npr * 4] = *(const ushort4*)(VThi + idx);
        *(ushort4*)&Vl[sd * GPD + npr * 4] = *(const ushort4*)(VTlo + idx);
      }
    }
    __syncthreads();
#pragma unroll
    for (int ks = 0; ks < 2; ++ks) {
      const int ko = fk + (ks << 5);
      short8v a_h[4], a_l[4];
#pragma unroll
      for (int i = 0; i < 4; ++i) {
        const int ar = (wr * 64 + i * 16 + fr) * GPD + ko;
        a_h[i] = *(const short8v*)&Ath[ar];
        a_l[i] = *(const short8v*)&Atl[ar];
      }
#pragma unroll
      for (int j = 0; j < 6; ++j) {
        if (skipj && j >= 2) continue;
        const int c = wc * 96 + j * 16 + fr;
        short8v b_h, b_l;
        if (wc * 96 + j * 16 < 128) {
          b_h = *(const short8v*)&Ath[c * GPD + ko];
          b_l = *(const short8v*)&Atl[c * GPD + ko];
        } else {
          b_h = *(const short8v*)&Vh[(c - 128) * GPD + ko];
          b_l = *(const short8v*)&Vl[(c - 128) * GPD + ko];
        }
#pragma unroll
        for (int i = 0; i < 4; ++i) {
          acc[i][j] = __builtin_amdgcn_mfma_f32_16x16x32_bf16(a_h[i], b_h, acc[i][j], 0, 0, 0);
          acc[i][j] = __builtin_amdgcn_mfma_f32_16x16x32_bf16(a_h[i], b_l, acc[i][j], 0, 0, 0);
          acc[i][j] = __builtin_amdgcn_mfma_f32_16x16x32_bf16(a_l[i], b_h, acc[i][j], 0, 0, 0);
        }
      }
    }
  }
  const int rb = wr * 64 + ((lane >> 4) << 2);
  const size_t gob = (size_t)(sp * 64 + bh) * 16384;
  const size_t pob = (size_t)(sp * 64 + bh) * 8192;
#pragma unroll
  for (int j = 0; j < 6; ++j) {
    if (skipj && j >= 2) continue;
    const int c = wc * 96 + j * 16 + fr;
#pragma unroll
    for (int i = 0; i < 4; ++i) {
      const int m0 = rb + i * 16;
      if (wc * 96 + j * 16 < 128) {
#pragma unroll
        for (int r = 0; r < 4; ++r) GPart[gob + (size_t)(m0 + r) * 128 + c] = acc[i][j][r];
      } else {
#pragma unroll
        for (int r = 0; r < 4; ++r) PPart[pob + (size_t)(m0 + r) * 64 + (c - 128)] = acc[i][j][r];
      }
    }
  }
}

// ---------------------------------------------------------------------------
__global__ __launch_bounds__(256) void reduce4_kernel(
    const float* __restrict__ part, float* __restrict__ out, int n, size_t cs)
{
  const int i = blockIdx.x * 256 + threadIdx.x;
  if (i < n) out[i] = (part[i] + part[cs + i]) + (part[2*cs + i] + part[3*cs + i]);
}

// ---------------------------------------------------------------------------
// yy partials from VT3: yyp[ch*64+bh] = sum over n-chunk of (hi+lo)^2
// ---------------------------------------------------------------------------
__global__ __launch_bounds__(256) void yy_vt(
    const unsigned short* __restrict__ VThi, const unsigned short* __restrict__ VTlo,
    float* __restrict__ yyp)
{
  const int bh = blockIdx.x, ch = blockIdx.y, tid = threadIdx.x;
  float s = 0.f;
  for (int t = tid; t < 4096; t += 256) {
    const int d = t & 63, npr = t >> 6;
    const size_t idx = ((size_t)(ch * 64 + npr) * 4096 + bh * 64 + d) << 2;
    ushort4 h4 = *(const ushort4*)(VThi + idx);
    ushort4 l4 = *(const ushort4*)(VTlo + idx);
    float v;
    v = bf2f(h4.x) + bf2f(l4.x); s = fmaf(v, v, s);
    v = bf2f(h4.y) + bf2f(l4.y); s = fmaf(v, v, s);
    v = bf2f(h4.z) + bf2f(l4.z); s = fmaf(v, v, s);
    v = bf2f(h4.w) + bf2f(l4.w); s = fmaf(v, v, s);
  }
  __shared__ float red[256];
  red[tid] = s; __syncthreads();
  for (int st = 128; st > 0; st >>= 1) {
    if (tid < st) red[tid] += red[tid + st];
    __syncthreads();
  }
  if (tid == 0) yyp[ch * 64 + bh] = red[0];
}

// ---------------------------------------------------------------------------
// Blocked batched Cholesky (NB=16), 256 threads.
// Swizzle f(i)=(i^(i>>2))&7: conflict-free for stride-1 AND stride-4 rows.
// ---------------------------------------------------------------------------
#define SWZ(i) ((((i) ^ ((i) >> 2)) & 7) << 2)
#define ELX(i,j)  As[(((i) << 7) + ((j) ^ SWZ(i)))]
#define EL4P(i,j4) (*(float4*)&As[(((i) << 7) + ((j4) ^ SWZ(i)))])

__global__ __launch_bounds__(256) void chol4_kernel(
    const float* __restrict__ Gk, const float* __restrict__ Go, const float* __restrict__ Cq,
    float* __restrict__ Lk, float* __restrict__ Lo, float* __restrict__ LTq, float* __restrict__ LTk,
    float* __restrict__ ldbuf, float* __restrict__ Dinvb)
{
  __shared__ float As[128*128];
  const int bh = blockIdx.x, which = blockIdx.y, tid = threadIdx.x;
  const float* G1; const float* G2 = nullptr; float* Lout;
  if (which == 0)      { G1 = Gk; Lout = Lk;  }
  else if (which == 1) { G1 = Go; Lout = Lo;  }
  else if (which == 2) { G1 = Go; G2 = Cq; Lout = LTq; }
  else                 { G1 = Go; G2 = Gk; Lout = LTk; }
  const size_t base = (size_t)bh * 16384;
  for (int t = tid; t < 16384; t += 256) {
    float v = G1[base + t];
    if (G2) v = fmaf(5.f, G2[base + t], v);
    const int i = t >> 7, j = t & 127;
    if (i == j) v += 0.01f;
    ELX(i, j) = v;
  }
  __syncthreads();

  float ldacc = 0.f;
  for (int kb = 0; kb < 8; ++kb) {
    const int k0 = kb << 4;
    const int rbase = k0 + 16;
    const int R = 128 - rbase;
    float Dg[16][16];
    float dinv[16];
    if (tid < 128) {
#pragma unroll
      for (int j = 0; j < 16; ++j) {
#pragma unroll
        for (int p4 = 0; p4 < 16; p4 += 4) {
          float4 q = EL4P(k0 + j, k0 + p4);
          Dg[j][p4] = q.x; Dg[j][p4+1] = q.y; Dg[j][p4+2] = q.z; Dg[j][p4+3] = q.w;
        }
      }
#pragma unroll
      for (int kk = 0; kk < 16; ++kk) {
        const float d = sqrtf(Dg[kk][kk]);
        Dg[kk][kk] = d;
        const float di = 1.f / d;
        dinv[kk] = di;
#pragma unroll
        for (int r = 0; r < 16; ++r) if (r > kk) Dg[r][kk] *= di;
#pragma unroll
        for (int r = 0; r < 16; ++r) if (r > kk)
#pragma unroll
          for (int c2 = 0; c2 < 16; ++c2) if (c2 > kk && c2 <= r)
            Dg[r][c2] = fmaf(-Dg[r][kk], Dg[c2][kk], Dg[r][c2]);
      }
      if (tid == 0) {
#pragma unroll
        for (int kk = 0; kk < 16; ++kk) ldacc += logf(Dg[kk][kk]);
#pragma unroll
        for (int j = 0; j < 16; ++j) {
#pragma unroll
          for (int p4 = 0; p4 < 16; p4 += 4) {
            float4 q = {Dg[j][p4], Dg[j][p4+1], Dg[j][p4+2], Dg[j][p4+3]};
            EL4P(k0 + j, k0 + p4) = q;
          }
        }
      }
    }
    if (tid < R) {
      const int r = rbase + tid;
      float xr[16];
#pragma unroll
      for (int p4 = 0; p4 < 16; p4 += 4) {
        float4 q = EL4P(r, k0 + p4);
        xr[p4] = q.x; xr[p4+1] = q.y; xr[p4+2] = q.z; xr[p4+3] = q.w;
      }
#pragma unroll
      for (int j = 0; j < 16; ++j) {
        float s = xr[j];
#pragma unroll
        for (int p = 0; p < 16; ++p) if (p < j) s = fmaf(-Dg[j][p], xr[p], s);
        xr[j] = s * dinv[j];
      }
#pragma unroll
      for (int p4 = 0; p4 < 16; p4 += 4) {
        float4 q = {xr[p4], xr[p4+1], xr[p4+2], xr[p4+3]};
        EL4P(r, k0 + p4) = q;
      }
    }
    __syncthreads();
    if (R > 0) {
      const int Rt = R >> 2;
      const int T = (Rt * (Rt + 1)) >> 1;
      for (int idx = tid; idx < T; idx += 256) {
        int ti = (int)((sqrtf(8.f * (float)idx + 1.f) - 1.f) * 0.5f);
        while (((ti + 1) * (ti + 2)) / 2 <= idx) ++ti;
        while ((ti * (ti + 1)) / 2 > idx) --ti;
        const int tj = idx - (ti * (ti + 1)) / 2;
        const int i0 = rbase + (ti << 2), j0 = rbase + (tj << 2);
        float Li[4][16], Lj[4][16];
#pragma unroll
        for (int a = 0; a < 4; ++a)
#pragma unroll
          for (int p4 = 0; p4 < 16; p4 += 4) {
            float4 q = EL4P(i0 + a, k0 + p4);
            Li[a][p4] = q.x; Li[a][p4+1] = q.y; Li[a][p4+2] = q.z; Li[a][p4+3] = q.w;
          }
#pragma unroll
        for (int a = 0; a < 4; ++a)
#pragma unroll
          for (int p4 = 0; p4 < 16; p4 += 4) {
            float4 q = EL4P(j0 + a, k0 + p4);
            Lj[a][p4] = q.x; Lj[a][p4+1] = q.y; Lj[a][p4+2] = q.z; Lj[a][p4+3] = q.w;
          }
        float4 cc[4];
#pragma unroll
        for (int a = 0; a < 4; ++a) cc[a] = EL4P(i0 + a, j0);
#pragma unroll
        for (int p = 0; p < 16; ++p)
#pragma unroll
          for (int a = 0; a < 4; ++a) {
            cc[a].x = fmaf(-Li[a][p], Lj[0][p], cc[a].x);
            cc[a].y = fmaf(-Li[a][p], Lj[1][p], cc[a].y);
            cc[a].z = fmaf(-Li[a][p], Lj[2][p], cc[a].z);
            cc[a].w = fmaf(-Li[a][p], Lj[3][p], cc[a].w);
          }
#pragma unroll
        for (int a = 0; a < 4; ++a) EL4P(i0 + a, j0) = cc[a];
      }
    }
    __syncthreads();
  }
  for (int t = tid; t < 16384; t += 256) {
    const int i = t >> 7, j = t & 127;
    Lout[base + t] = (j <= i) ? ELX(i, j) : ELX(j, i);
  }
  if (tid < 128) Dinvb[(size_t)which * 8192 + bh * 128 + tid] = 1.f / ELX(tid, tid);
  if (tid == 0) ldbuf[which * 64 + bh] = 2.f * ldacc;
}

// ---------------------------------------------------------------------------
// Blocked batched cho_solve (NB=16), 256 threads.
// ---------------------------------------------------------------------------
__global__ __launch_bounds__(256) void solve5_kernel(
    const float* __restrict__ Lk, const float* __restrict__ Lo,
    const float* __restrict__ LTq, const float* __restrict__ LTk,
    const float* __restrict__ Dinvb,
    const float* __restrict__ PkTv, const float* __restrict__ PhiTy,
    const float* __restrict__ Cq, const float* __restrict__ Gk,
    float* __restrict__ Z1, float* __restrict__ Aoi,
    float* __restrict__ Z2, float* __restrict__ Wq2, float* __restrict__ Wk2)
{
  __shared__ alignas(16) float Xs[128][128];
  __shared__ alignas(16) float Lp[128][16];
  __shared__ float di[128];
  const int bh = blockIdx.x, which = blockIdx.y, tid = threadIdx.x;
  const float* Lsrc; const float* Bsrc; float* Out; int nr; int mat;
  if (which == 0)      { Lsrc = Lk;  Bsrc = PkTv;    Out = Z1;  nr = 64;  mat = 0; }
  else if (which == 1) { Lsrc = Lo;  Bsrc = nullptr; Out = Aoi; nr = 128; mat = 1; }
  else if (which == 2) { Lsrc = LTq; Bsrc = PhiTy;   Out = Z2;  nr = 64;  mat = 2; }
  else if (which == 3) { Lsrc = LTq; Bsrc = Cq;      Out = Wq2; nr = 128; mat = 2; }
  else                 { Lsrc = LTk; Bsrc = Gk;      Out = Wk2; nr = 128; mat = 3; }
  const size_t baseL = (size_t)bh * 16384;
  const size_t baseB = (size_t)bh * 128 * (size_t)nr;
  const int sh = (nr == 64) ? 6 : 7, mk2 = nr - 1;
  if (Bsrc) {
    for (int t = tid; t < 128 * nr; t += 256) Xs[t >> sh][t & mk2] = Bsrc[baseB + t];
  } else {
    for (int t = tid; t < 16384; t += 256)
      Xs[t >> 7][t & 127] = ((t >> 7) == (t & 127)) ? 1.f : 0.f;
  }
  if (tid < 128) di[tid] = Dinvb[(size_t)mat * 8192 + bh * 128 + tid];
  const int c0 = (nr == 128) ? ((tid & 31) << 2) : ((tid & 15) << 2);
  const int rg = (nr == 128) ? (tid >> 5) : (tid >> 4);
  const int rstride = (nr == 128) ? 8 : 16;
  __syncthreads();
  for (int kb = 0; kb < 8; ++kb) {
    const int k0 = kb << 4;
    const int nrow = 128 - k0;
    for (int t = tid; t < nrow * 4; t += 256) {
      const int pr = t >> 2, pc = (t & 3) << 2;
      *(float4*)&Lp[pr][pc] = *(const float4*)(Lsrc + baseL + (size_t)(k0 + pr) * 128 + k0 + pc);
    }
    __syncthreads();
    if (tid < nr) {
      float xb[16];
#pragma unroll
      for (int j = 0; j < 16; ++j) {
        float s = Xs[k0 + j][tid];
#pragma unroll
        for (int p = 0; p < 16; ++p) if (p < j) s = fmaf(-Lp[j][p], xb[p], s);
        xb[j] = s * di[k0 + j];
        Xs[k0 + j][tid] = xb[j];
      }
    }
    __syncthreads();
    if (k0 + 16 < 128) {
      float4 xb4[16];
#pragma unroll
      for (int p = 0; p < 16; ++p) xb4[p] = *(const float4*)&Xs[k0 + p][c0];
      for (int r = k0 + 16 + rg; r < 128; r += rstride) {
        float4 xv = *(const float4*)&Xs[r][c0];
#pragma unroll
        for (int p = 0; p < 16; ++p) {
          const float l = Lp[r - k0][p];
          xv.x = fmaf(-l, xb4[p].x, xv.x);
          xv.y = fmaf(-l, xb4[p].y, xv.y);
          xv.z = fmaf(-l, xb4[p].z, xv.z);
          xv.w = fmaf(-l, xb4[p].w, xv.w);
        }
        *(float4*)&Xs[r][c0] = xv;
      }
    }
    __syncthreads();
  }
  for (int kb = 7; kb >= 0; --kb) {
    const int k0 = kb << 4;
    const int nrow = k0 + 16;
    for (int t = tid; t < nrow * 4; t += 256) {
      const int pr = t >> 2, pc = (t & 3) << 2;
      *(float4*)&Lp[pr][pc] = *(const float4*)(Lsrc + baseL + (size_t)pr * 128 + k0 + pc);
    }
    __syncthreads();
    if (tid < nr) {
      float xb[16];
#pragma unroll
      for (int j = 15; j >= 0; --j) {
        float s = Xs[k0 + j][tid];
#pragma unroll
        for (int p = 0; p < 16; ++p) if (p > j) s = fmaf(-Lp[k0 + j][p], xb[p], s);
        xb[j] = s * di[k0 + j];
        Xs[k0 + j][tid] = xb[j];
      }
    }
    __syncthreads();
    if (k0 > 0) {
      float4 xb4[16];
#pragma unroll
      for (int p = 0; p < 16; ++p) xb4[p] = *(const float4*)&Xs[k0 + p][c0];
      for (int r = rg; r < k0; r += rstride) {
        float4 xv = *(const float4*)&Xs[r][c0];
#pragma unroll
        for (int p = 0; p < 16; ++p) {
          const float l = Lp[r][p];
          xv.x = fmaf(-l, xb4[p].x, xv.x);
          xv.y = fmaf(-l, xb4[p].y, xv.y);
          xv.z = fmaf(-l, xb4[p].z, xv.z);
          xv.w = fmaf(-l, xb4[p].w, xv.w);
        }
        *(float4*)&Xs[r][c0] = xv;
      }
    }
    __syncthreads();
  }
  for (int t = tid; t < 128 * nr; t += 256) Out[baseB + t] = Xs[t >> sh][t & mk2];
}

// ---------------------------------------------------------------------------
// mid = Z1 - 0.01 * Aoi @ Z1   (Aoi symmetric)
// ---------------------------------------------------------------------------
__global__ __launch_bounds__(256) void mid_kernel(
    const float* __restrict__ Aoi, const float* __restrict__ Z1,
    float* __restrict__ midb)
{
  __shared__ alignas(16) float Ao[128][128];
  __shared__ alignas(16) float Z[128][64];
  const int bh = blockIdx.x, tid = threadIdx.x;
  const size_t bM = (size_t)bh * 16384, bD = (size_t)bh * 8192;
  for (int t4 = tid; t4 < 4096; t4 += 256) {
    const int r = t4 >> 5, c4 = (t4 & 31) << 2;
    *(float4*)&Ao[r][c4] = *(const float4*)(Aoi + bM + (size_t)r*128 + c4);
  }
  for (int t4 = tid; t4 < 2048; t4 += 256) {
    const int r = t4 >> 4, c4 = (t4 & 15) << 2;
    *(float4*)&Z[r][c4] = *(const float4*)(Z1 + bD + (size_t)r*64 + c4);
  }
  __syncthreads();
  const int ty = tid >> 4, tx = tid & 15;
  float acc[8][4];
#pragma unroll
  for (int i = 0; i < 8; ++i)
#pragma unroll
    for (int j = 0; j < 4; ++j) acc[i][j] = 0.f;
  for (int kk = 0; kk < 128; ++kk) {
    float4 a0 = *(const float4*)&Ao[kk][ty*8];
    float4 a1 = *(const float4*)&Ao[kk][ty*8+4];
    float4 bv = *(const float4*)&Z[kk][tx*4];
    float a[8] = {a0.x, a0.y, a0.z, a0.w, a1.x, a1.y, a1.z, a1.w};
    float b[4] = {bv.x, bv.y, bv.z, bv.w};
#pragma unroll
    for (int i = 0; i < 8; ++i)
#pragma unroll
      for (int j = 0; j < 4; ++j) acc[i][j] = fmaf(a[i], b[j], acc[i][j]);
  }
#pragma unroll
  for (int i = 0; i < 8; ++i) {
    const int r = ty*8 + i, c = tx*4;
    float4 o;
    o.x = Z[r][c+0] - 0.01f*acc[i][0];
    o.y = Z[r][c+1] - 0.01f*acc[i][1];
    o.z = Z[r][c+2] - 0.01f*acc[i][2];
    o.w = Z[r][c+3] - 0.01f*acc[i][3];
    *(float4*)(midb + bD + (size_t)r*64 + c) = o;
  }
}

// ---------------------------------------------------------------------------
// Pq = Cq @ Wq2 ; Pk = Gk @ Wk2   (A operand symmetric)
// ---------------------------------------------------------------------------
__global__ __launch_bounds__(256) void pmat_kernel(
    const float* __restrict__ Cq, const float* __restrict__ Wq2,
    const float* __restrict__ Gk, const float* __restrict__ Wk2,
    float* __restrict__ Pq, float* __restrict__ Pk)
{
  __shared__ alignas(16) float Am[128][128];
  __shared__ alignas(16) float Bm[128][128];
  const int bh = blockIdx.x, which = blockIdx.y, tid = threadIdx.x;
  const float* Ap = which ? Gk : Cq;
  const float* Bp = which ? Wk2 : Wq2;
  float* Op = which ? Pk : Pq;
  const size_t base = (size_t)bh * 16384;
  for (int t4 = tid; t4 < 4096; t4 += 256) {
    const int r = t4 >> 5, c4 = (t4 & 31) << 2;
    *(float4*)&Am[r][c4] = *(const float4*)(Ap + base + (size_t)r*128 + c4);
    *(float4*)&Bm[r][c4] = *(const float4*)(Bp + base + (size_t)r*128 + c4);
  }
  __syncthreads();
  const int ty = tid >> 4, tx = tid & 15;
  float acc[8][8];
#pragma unroll
  for (int i = 0; i < 8; ++i)
#pragma unroll
    for (int j = 0; j < 8; ++j) acc[i][j] = 0.f;
  for (int kk = 0; kk < 128; ++kk) {
    float4 av0 = *(const float4*)&Am[kk][ty*8];
    float4 av1 = *(const float4*)&Am[kk][ty*8+4];
    float4 bv0 = *(const float4*)&Bm[kk][tx*8];
    float4 bv1 = *(const float4*)&Bm[kk][tx*8+4];
    float a[8] = {av0.x, av0.y, av0.z, av0.w, av1.x, av1.y, av1.z, av1.w};
    float b[8] = {bv0.x, bv0.y, bv0.z, bv0.w, bv1.x, bv1.y, bv1.z, bv1.w};
#pragma unroll
    for (int i = 0; i < 8; ++i)
#pragma unroll
      for (int j = 0; j < 8; ++j) acc[i][j] = fmaf(a[i], b[j], acc[i][j]);
  }
#pragma unroll
  for (int i = 0; i < 8; ++i)
#pragma unroll
    for (int j = 0; j < 8; j += 4) {
      float4 o = {acc[i][j], acc[i][j+1], acc[i][j+2], acc[i][j+3]};
      *(float4*)(Op + base + (size_t)(ty*8+i)*128 + tx*8 + j) = o;
    }
}

// ---------------------------------------------------------------------------
__global__ __launch_bounds__(256) void scalars_kernel(
    const float* __restrict__ Aoi, const float* __restrict__ Cq, const float* __restrict__ Gk,
    const float* __restrict__ Pq, const float* __restrict__ Pk, const float* __restrict__ Wk2,
    const float* __restrict__ PhiTy, const float* __restrict__ Z2,
    const float* __restrict__ yyp, const float* __restrict__ ldb,
    float* __restrict__ regp)
{
  const int bh = blockIdx.x, tid = threadIdx.x;
  const size_t b0 = (size_t)bh * 16384, b1 = (size_t)bh * 8192;
  double aoCq=0, aoGk=0, aoPq=0, aoPk=0, wkGk=0, trCq=0, trGk=0, trPq=0, trPk=0, s1=0;
  for (int t = tid; t < 16384; t += 256) {
    const double ao = Aoi[b0+t], cq = Cq[b0+t], gk = Gk[b0+t];
    const double pq = Pq[b0+t], pk = Pk[b0+t], wk = Wk2[b0+t];
    aoCq += ao*cq; aoGk += ao*gk; aoPq += ao*pq; aoPk += ao*pk; wkGk += wk*gk;
    if (t % 129 == 0) { trCq += cq; trGk += gk; trPq += pq; trPk += pk; }
  }
  for (int t = tid; t < 8192; t += 256) s1 += (double)PhiTy[b1+t] * (double)Z2[b1+t];
  __shared__ double red[256];
  double vals[10] = {aoCq, aoGk, aoPq, aoPk, wkGk, trCq, trGk, trPq, trPk, s1};
  double tot[10];
  for (int vv = 0; vv < 10; ++vv) {
    red[tid] = vals[vv];
    __syncthreads();
    for (int st = 128; st > 0; st >>= 1) {
      if (tid < st) red[tid] += red[tid+st];
      __syncthreads();
    }
    tot[vv] = red[0];
    __syncthreads();
  }
  if (tid == 0) {
    const double D = 64.0, Nd = 2048.0;
    const double ldAo = ldb[64 + bh], ldTq = ldb[128 + bh], ldTk = ldb[192 + bh];
    double yv = 0.0;
    for (int c = 0; c < 8; ++c) yv += (double)yyp[c * 64 + bh];
    const double cst  = Nd * log(2.0 * 3.14159265358979323846);
    const double leps = Nd * log(0.002);
    const double datq = 500.0*yv - 2500.0*tot[9];
    const double modq = D*(500.0*tot[5] - 2500.0*tot[7] - 0.01*(500.0*tot[0] - 2500.0*tot[2]));
    const double ldq  = leps + ldTq - ldAo;
    const double LBq  = -0.5*(datq + modq + ldq + cst);
    const double datk = D*(500.0*tot[6] - 2500.0*tot[4]);
    const double modk = D*(500.0*tot[6] - 2500.0*tot[8] - 0.01*(500.0*tot[1] - 2500.0*tot[3]));
    const double ldk  = leps + ldTk - ldAo;
    const double LBk  = -0.5*(datk + modk + ldk + cst);
    regp[bh] = (float)(-(LBq + LBk) / 64.0);
  }
}

__global__ void regfinal_kernel(const float* __restrict__ regp, float* __restrict__ outp)
{
  __shared__ float red[64];
  const int tid = threadIdx.x;
  red[tid] = regp[tid];
  __syncthreads();
  for (int st = 32; st > 0; st >>= 1) {
    if (tid < st) red[tid] += red[tid+st];
    __syncthreads();
  }
  if (tid == 0) outp[0] = red[0];
}

// ---------------------------------------------------------------------------
// y = Phi_q @ mid -> emitted as bf16 hi/lo natural layout (feeds gemm_out B).
// Phi_q read from PT3 packed layout.
// ---------------------------------------------------------------------------
__global__ __launch_bounds__(256) void y_kernel(
    const unsigned short* __restrict__ PThi, const unsigned short* __restrict__ PTlo,
    const float* __restrict__ midb,
    unsigned short* __restrict__ Yhi, unsigned short* __restrict__ Ylo)
{
  __shared__ float Ps[128][129];   // Ps[n][m], padded
  __shared__ alignas(16) float Ms[128][64];
  const int blk = blockIdx.x;
  const int bh = blk >> 4, nt = blk & 15;
  const int b = bh >> 3, h = bh & 7;
  const int n0 = nt << 7;
  const int tid = threadIdx.x;
  for (int t = tid; t < 4096; t += 256) {
    const int m = t & 127, npr = t >> 7;   // npr 0..31 covers 128 n
    const size_t idx = ((size_t)((n0 >> 2) + npr) * 8192 + bh * 128 + m) << 2;
    ushort4 h4 = *(const ushort4*)(PThi + idx);
    ushort4 l4 = *(const ushort4*)(PTlo + idx);
    Ps[npr*4+0][m] = bf2f(h4.x) + bf2f(l4.x);
    Ps[npr*4+1][m] = bf2f(h4.y) + bf2f(l4.y);
    Ps[npr*4+2][m] = bf2f(h4.z) + bf2f(l4.z);
    Ps[npr*4+3][m] = bf2f(h4.w) + bf2f(l4.w);
  }
  for (int t4 = tid; t4 < 2048; t4 += 256) {
    const int r = t4 >> 4, c4 = (t4 & 15) << 2;
    *(float4*)&Ms[r][c4] = *(const float4*)(midb + (size_t)bh*8192 + (size_t)r*64 + c4);
  }
  __syncthreads();
  const int ty = tid >> 4, tx = tid & 15;
  float acc[8][4];
#pragma unroll
  for (int i = 0; i < 8; ++i)
#pragma unroll
    for (int j = 0; j < 4; ++j) acc[i][j] = 0.f;
  for (int kk = 0; kk < 128; ++kk) {
    float4 bv = *(const float4*)&Ms[kk][tx*4];
    float b4[4] = {bv.x, bv.y, bv.z, bv.w};
#pragma unroll
    for (int i = 0; i < 8; ++i) {
      const float a = Ps[ty*8+i][kk];
      acc[i][0] = fmaf(a, b4[0], acc[i][0]);
      acc[i][1] = fmaf(a, b4[1], acc[i][1]);
      acc[i][2] = fmaf(a, b4[2], acc[i][2]);
      acc[i][3] = fmaf(a, b4[3], acc[i][3]);
    }
  }
#pragma unroll
  for (int i = 0; i < 8; ++i) {
    const size_t addr = ((size_t)(b*N_) + n0 + ty*8 + i)*512 + h*64 + tx*4;
    ushort4 hv, lv;
    hv.x = f2bf(acc[i][0]); lv.x = f2bf(acc[i][0] - bf2f(hv.x));
    hv.y = f2bf(acc[i][1]); lv.y = f2bf(acc[i][1] - bf2f(hv.y));
    hv.z = f2bf(acc[i][2]); lv.z = f2bf(acc[i][2] - bf2f(hv.z));
    hv.w = f2bf(acc[i][3]); lv.w = f2bf(acc[i][3] - bf2f(hv.w));
    *(ushort4*)(Yhi + addr) = hv;
    *(ushort4*)(Ylo + addr) = lv;
  }
}

// ---------------------------------------------------------------------------
extern "C" void kernel_launch(void* const* d_in, const int* in_sizes, int n_in,
                              void* d_out, int out_size, void* d_ws, size_t ws_size,
                              hipStream_t stream)
{
  const float* x     = (const float*)d_in[0];
  const float* mask  = (const float*)d_in[1];
  const float* Wq    = (const float*)d_in[2];
  const float* bq    = (const float*)d_in[3];
  const float* Wk    = (const float*)d_in[4];
  const float* bk    = (const float*)d_in[5];
  const float* Wv    = (const float*)d_in[6];
  const float* bv    = (const float*)d_in[7];
  const float* Wx0   = (const float*)d_in[8];
  const float* bx0   = (const float*)d_in[9];
  const float* Wo    = (const float*)d_in[10];
  const float* bo    = (const float*)d_in[11];
  const float* omega = (const float*)d_in[12];
  const float* brff  = (const float*)d_in[13];
  float* outp = (float*)d_out;

  float* W_ = (float*)d_ws;
  size_t off = 0;
  auto take = [&](size_t n) -> float* { float* p = W_ + off; off += n; return p; };
  const size_t SZ_BNH = (size_t)8*2048*512;    // 8,388,608
  const size_t SZ_MM  = (size_t)64*128*128;    // 1,048,576
  const size_t SZ_MD  = (size_t)64*128*64;     //   524,288

  unsigned short* Xhi  = (unsigned short*)take(SZ_BNH/2);
  unsigned short* Xlo  = (unsigned short*)take(SZ_BNH/2);
  unsigned short* PThi = (unsigned short*)take(SZ_BNH);
  unsigned short* PTlo = (unsigned short*)take(SZ_BNH);
  unsigned short* VThi = (unsigned short*)take(SZ_BNH/2);
  unsigned short* VTlo = (unsigned short*)take(SZ_BNH/2);
  unsigned short* WOmH = (unsigned short*)take(786432);
  unsigned short* WOmL = (unsigned short*)take(786432);
  float* bias2 = take(3072);
  unsigned short* WvH = (unsigned short*)take(131072);
  unsigned short* WvL = (unsigned short*)take(131072);
  unsigned short* WoH = (unsigned short*)take(131072);
  unsigned short* WoL = (unsigned short*)take(131072);
  float* Gk   = take(SZ_MM);
  float* Go   = take(SZ_MM);
  float* Cq   = take(SZ_MM);
  float* Lk   = take(SZ_MM);
  float* Lo   = take(SZ_MM);
  float* LTq  = take(SZ_MM);
  float* LTk  = take(SZ_MM);
  float* Aoi  = take(SZ_MM);
  float* Wq2  = take(SZ_MM);
  float* Wk2  = take(SZ_MM);
  float* Pq   = take(SZ_MM);
  float* Pk   = take(SZ_MM);
  float* PkTv = take(SZ_MD);
  float* PhiTy= take(SZ_MD);
  float* Z1   = take(SZ_MD);
  float* Z2   = take(SZ_MD);
  float* midb = take(SZ_MD);
  float* GPart= take(4*SZ_MM);
  float* PPart= take(4*SZ_MD);
  float* Dinv = take(4*64*128);
  float* yyp  = take(512);
  float* ldb  = take(256);
  float* regp = take(64);
  (void)ws_size; (void)in_sizes; (void)n_in; (void)out_size;

  // input prep
  split_kernel<<<8192, 256, 0, stream>>>(x, Xhi, Xlo, (int)SZ_BNH);
  split_kernel<<<256, 256, 0, stream>>>(Wv, WvH, WvL, 262144);
  split_kernel<<<256, 256, 0, stream>>>(Wo, WoH, WoL, 262144);
  womb_kernel<<<3072, 256, 0, stream>>>(Wq, Wk, Wx0, bq, bk, bx0, omega, brff,
                                        WOmH, WOmL, bias2);
  // v path -> VT3, yy
  gemm_vt<<<512, 256, 0, stream>>>(Xhi, Xlo, WvH, WvL, bv, mask, VThi, VTlo);
  yy_vt<<<dim3(64, 8), 256, 0, stream>>>(VThi, VTlo, yyp);
  // x0 path -> Go   (path index 2 in WOm)
  gemm_rff<<<1024, 256, 0, stream>>>(Xhi, Xlo, WOmH + 2*524288, WOmL + 2*524288,
                                     bias2 + 2048, mask, PThi, PTlo);
  gram_ptv<<<dim3(64, 4), 256, 0, stream>>>(PThi, PTlo, VThi, VTlo, GPart, PPart, 0);
  reduce4_kernel<<<4096, 256, 0, stream>>>(GPart, Go, 1048576, (size_t)1048576);
  // k path -> Gk, PkTv  (path 1)
  gemm_rff<<<1024, 256, 0, stream>>>(Xhi, Xlo, WOmH + 1*524288, WOmL + 1*524288,
                                     bias2 + 1024, mask, PThi, PTlo);
  gram_ptv<<<dim3(64, 4), 256, 0, stream>>>(PThi, PTlo, VThi, VTlo, GPart, PPart, 1);
  reduce4_kernel<<<4096, 256, 0, stream>>>(GPart, Gk, 1048576, (size_t)1048576);
  reduce4_kernel<<<2048, 256, 0, stream>>>(PPart, PkTv, 524288, (size_t)524288);
  // q path -> Cq, PhiTy  (path 0; PT3 stays live for y_kernel)
  gemm_rff<<<1024, 256, 0, stream>>>(Xhi, Xlo, WOmH, WOmL,
                                     bias2, mask, PThi, PTlo);
  gram_ptv<<<dim3(64, 4), 256, 0, stream>>>(PThi, PTlo, VThi, VTlo, GPart, PPart, 1);
  reduce4_kernel<<<4096, 256, 0, stream>>>(GPart, Cq, 1048576, (size_t)1048576);
  reduce4_kernel<<<2048, 256, 0, stream>>>(PPart, PhiTy, 524288, (size_t)524288);
  // batched linear algebra
  chol4_kernel<<<dim3(64, 4), 256, 0, stream>>>(Gk, Go, Cq, Lk, Lo, LTq, LTk, ldb, Dinv);
  solve5_kernel<<<dim3(64, 5), 256, 0, stream>>>(Lk, Lo, LTq, LTk, Dinv, PkTv, PhiTy, Cq, Gk,
                                                 Z1, Aoi, Z2, Wq2, Wk2);
  mid_kernel<<<64, 256, 0, stream>>>(Aoi, Z1, midb);
  pmat_kernel<<<dim3(64, 2), 256, 0, stream>>>(Cq, Wq2, Gk, Wk2, Pq, Pk);
  scalars_kernel<<<64, 256, 0, stream>>>(Aoi, Cq, Gk, Pq, Pk, Wk2, PhiTy, Z2, yyp, ldb, regp);
  regfinal_kernel<<<1, 64, 0, stream>>>(regp, outp + SZ_BNH);
  // output path: y -> bf16 hi/lo natural layout (reusing Xhi/Xlo), then
  // operand-swapped projection (A=Wo rows=cols, B=y rows=rows).
  y_kernel<<<1024, 256, 0, stream>>>(PThi, PTlo, midb, Xhi, Xlo);
  gemm_out<<<512, 256, 0, stream>>>(WoH, WoL, Xhi, Xlo, bo, outp);
}